// Round 7
// baseline (472.248 us; speedup 1.0000x reference)
//
#include <hip/hip_runtime.h>
#include <stdint.h>

#define B_ 2
#define S_ 4096
#define D_ 768
#define H_ 12
#define F_ 3072
#define DK_ 64
#define QBLK 128
#define KVB 64
#define NT (S_ / KVB)

typedef __bf16 bf16x8 __attribute__((ext_vector_type(8)));
typedef float floatx4 __attribute__((ext_vector_type(4)));
typedef float floatx16 __attribute__((ext_vector_type(16)));

__device__ __forceinline__ float bf2f(unsigned short u) {
  unsigned int x = ((unsigned int)u) << 16;
  return __builtin_bit_cast(float, x);
}
__device__ __forceinline__ unsigned short f2bf(float f) {
  unsigned int x = __builtin_bit_cast(unsigned int, f);
  x += 0x7FFFu + ((x >> 16) & 1u);
  return (unsigned short)(x >> 16);
}
__device__ __forceinline__ unsigned int cvtpk_bf16(float lo, float hi) {
  unsigned int r;
  asm("v_cvt_pk_bf16_f32 %0, %1, %2" : "=v"(r) : "v"(lo), "v"(hi));
  return r;
}

// ---------------- weight transpose + cvt: w[K][N] f32 -> wt[N][K] bf16 ----------------
__global__ __launch_bounds__(256) void wtrans(const float* __restrict__ w,
                                              unsigned short* __restrict__ wt,
                                              int K, int N) {
  __shared__ float tile[32][33];
  const int n0 = blockIdx.x * 32, k0 = blockIdx.y * 32;
  const int tx = threadIdx.x & 31, ty8 = threadIdx.x >> 5;
#pragma unroll
  for (int r = 0; r < 4; r++)
    tile[ty8 + r * 8][tx] = w[(size_t)(k0 + ty8 + r * 8) * N + n0 + tx];
  __syncthreads();
#pragma unroll
  for (int r = 0; r < 4; r++)
    wt[(size_t)(n0 + ty8 + r * 8) * K + k0 + tx] = f2bf(tile[tx][ty8 + r * 8]);
}

// ---------------- f32 -> bf16 bulk convert (8 elems/thread) ----------------
__global__ __launch_bounds__(256) void cvt_bf16(const float* __restrict__ x,
                                                unsigned short* __restrict__ y, int n8) {
  const int i = blockIdx.x * 256 + threadIdx.x;
  if (i >= n8) return;
  const float4 a = ((const float4*)x)[2 * i];
  const float4 b = ((const float4*)x)[2 * i + 1];
  uint4 o;
  o.x = (unsigned int)f2bf(a.x) | ((unsigned int)f2bf(a.y) << 16);
  o.y = (unsigned int)f2bf(a.z) | ((unsigned int)f2bf(a.w) << 16);
  o.z = (unsigned int)f2bf(b.x) | ((unsigned int)f2bf(b.y) << 16);
  o.w = (unsigned int)f2bf(b.z) | ((unsigned int)f2bf(b.w) << 16);
  ((uint4*)y)[i] = o;
}

// ---------------- GEMM (m97 structure, BK=64): out = A(bf16) @ Bt^T + bias ----------------
// 128x128 tile, BK=64, global_load_lds width-16, linear LDS, XCD swizzle.
// RESID_MODE: 0 none, 1 f32, 2 bf16.
template <bool RELU, int RESID_MODE, bool OUT_BF16>
__global__ __launch_bounds__(256, 2) void gemm_lds(
    const unsigned short* __restrict__ A, const unsigned short* __restrict__ Bt,
    const float* __restrict__ bias, const void* __restrict__ residv,
    void* __restrict__ outv, int M, int N, int K) {
  __shared__ __align__(16) unsigned short As[128 * 64];
  __shared__ __align__(16) unsigned short Bs[128 * 64];
  int bx = blockIdx.x, by = blockIdx.y;
  {
    const int gx = gridDim.x;
    const int nwg = gx * gridDim.y;       // all grids divisible by 8
    const int flat = by * gx + bx;
    const int wg = (flat & 7) * (nwg >> 3) + (flat >> 3);
    bx = wg % gx; by = wg / gx;
  }
  const int t = threadIdx.x;
  const int lane = t & 63, wave = t >> 6;
  const int m0 = by * 128, n0 = bx * 128;
  const int wm = (wave >> 1) * 64, wn = (wave & 1) * 64;
  const int rl = lane & 15, kl = (lane >> 4) * 8;
  const int lrow = lane >> 3, lcol = (lane & 7) * 8;

  floatx4 zf = {0.f, 0.f, 0.f, 0.f};
  floatx4 acc[4][4];
#pragma unroll
  for (int i = 0; i < 4; i++)
#pragma unroll
    for (int j = 0; j < 4; j++) acc[i][j] = zf;

  const unsigned short* Ab = A + (size_t)(m0 + wave * 32 + lrow) * K + lcol;
  const unsigned short* Bb = Bt + (size_t)(n0 + wave * 32 + lrow) * K + lcol;
  unsigned short* AsW = As + wave * 2048;  // wave-uniform LDS base (elements)
  unsigned short* BsW = Bs + wave * 2048;

  for (int k0 = 0; k0 < K; k0 += 64) {
    __syncthreads();  // previous tile's LDS reads done
#pragma unroll
    for (int ld = 0; ld < 4; ld++) {
      __builtin_amdgcn_global_load_lds(Ab + k0 + (size_t)(ld * 8) * K, AsW + ld * 512, 16, 0, 0);
      __builtin_amdgcn_global_load_lds(Bb + k0 + (size_t)(ld * 8) * K, BsW + ld * 512, 16, 0, 0);
    }
    __syncthreads();  // vmcnt drained by compiler before barrier
#pragma unroll
    for (int ks = 0; ks < 2; ks++) {
      bf16x8 af[4], bff[4];
#pragma unroll
      for (int i = 0; i < 4; i++)
        af[i] = __builtin_bit_cast(bf16x8, *(const uint4*)&As[(wm + i * 16 + rl) * 64 + ks * 32 + kl]);
#pragma unroll
      for (int j = 0; j < 4; j++)
        bff[j] = __builtin_bit_cast(bf16x8, *(const uint4*)&Bs[(wn + j * 16 + rl) * 64 + ks * 32 + kl]);
#pragma unroll
      for (int i = 0; i < 4; i++)
#pragma unroll
        for (int j = 0; j < 4; j++)
          acc[i][j] = __builtin_amdgcn_mfma_f32_16x16x32_bf16(af[i], bff[j], acc[i][j], 0, 0, 0);
    }
  }

  const int r0 = (lane >> 4) * 4;
#pragma unroll
  for (int i = 0; i < 4; i++) {
#pragma unroll
    for (int j = 0; j < 4; j++) {
      const int col = n0 + wn + j * 16 + rl;
      const float bv = bias[col];
#pragma unroll
      for (int r = 0; r < 4; r++) {
        const int row = m0 + wm + i * 16 + r0 + r;
        float v = acc[i][j][r] + bv;
        if (RESID_MODE == 1) v += ((const float*)residv)[(size_t)row * N + col];
        if (RESID_MODE == 2) v += bf2f(((const unsigned short*)residv)[(size_t)row * N + col]);
        if (RELU) v = v > 0.f ? v : 0.f;
        if (OUT_BF16)
          ((unsigned short*)outv)[(size_t)row * N + col] = f2bf(v);
        else
          ((float*)outv)[(size_t)row * N + col] = v;
      }
    }
  }
}

// ---------------- flash attention v4: dbuf single-barrier, hoisted mask ----------------
// 4 waves x 32 q rows; swapped QK^T (lane owns a q-row), in-register softmax (T12),
// double-buffered K/Vt LDS with one barrier per tile, T14 prefetch, T13 defer-max.
__global__ __launch_bounds__(256, 3) void flash_attn_v4(
    const unsigned short* __restrict__ qg, const unsigned short* __restrict__ kg,
    const unsigned short* __restrict__ vg, const int* __restrict__ maskg,
    unsigned short* __restrict__ ctx) {
  __shared__ __align__(16) unsigned short Ks[2][64][64];
  __shared__ __align__(16) unsigned short Vt[2][64][64];
  __shared__ unsigned char TFlag[NT];

  const int t = threadIdx.x;
  const int L = t & 63, wv = t >> 6;
  const int q5 = L & 31, h5 = L >> 5;
  const int qb = blockIdx.x, h = blockIdx.y, b = blockIdx.z;
  const size_t bS = (size_t)b * S_;
  const int hb = h * DK_;
  const unsigned short* kbase = kg + bS * D_ + hb;
  const unsigned short* vbase = vg + bS * D_ + hb;
  const int* mp = maskg + bS;

  // hoisted mask tile flags: wave wv handles tiles wv, wv+4, ...
  for (int tt = wv; tt < NT; tt += 4) {
    const int mv = mp[tt * KVB + L];
    const unsigned long long bal = __ballot(mv != 0);
    if (L == 0) TFlag[tt] = (bal == ~0ull) ? 1 : 0;
  }

  // Q as B-fragment: lane holds Q[q5][d = ks*16 + h5*8 + j]
  bf16x8 bq[4];
  {
    const unsigned short* qp = qg + (bS + qb * QBLK + wv * 32 + q5) * D_ + hb + h5 * 8;
#pragma unroll
    for (int ks = 0; ks < 4; ks++)
      bq[ks] = __builtin_bit_cast(bf16x8, *(const uint4*)(qp + ks * 16));
  }

  floatx16 o0, o1;
#pragma unroll
  for (int r = 0; r < 16; r++) { o0[r] = 0.f; o1[r] = 0.f; }
  float m_ = -1e30f, l_ = 0.f;

  const int skv = t >> 2, kc = (t & 3) * 2;
  const int cshift = q5 & 7;
  const int vsh0 = (q5 & 7) ^ (q5 >> 3);
  const int vsh1 = vsh0 ^ 4;

  uint4 kr0, kr1, vr0, vr1;
  // prologue: stage tile 0 into buf 0
  {
    const unsigned short* kp = kbase + (size_t)skv * D_ + kc * 8;
    const unsigned short* vp = vbase + (size_t)skv * D_ + kc * 8;
    kr0 = *(const uint4*)kp; kr1 = *(const uint4*)(kp + 8);
    vr0 = *(const uint4*)vp; vr1 = *(const uint4*)(vp + 8);
    *(uint4*)&Ks[0][skv][((kc) ^ (skv & 7)) * 8] = kr0;
    *(uint4*)&Ks[0][skv][((kc + 1) ^ (skv & 7)) * 8] = kr1;
    union { uint4 u; unsigned short e[8]; } a0, a1;
    a0.u = vr0; a1.u = vr1;
#pragma unroll
    for (int e = 0; e < 8; e++) {
      const int cp0 = (((skv >> 3) ^ e ^ kc) << 3) | (skv & 7);
      const int cp1 = (((skv >> 3) ^ e ^ (kc + 1)) << 3) | (skv & 7);
      Vt[0][kc * 8 + e][cp0] = a0.e[e];
      Vt[0][kc * 8 + 8 + e][cp1] = a1.e[e];
    }
  }
  __syncthreads();  // publish buf0 + TFlag

  for (int kt = 0; kt < NT; kt++) {
    const int cur = kt & 1;
    const int kv0 = kt * KVB;
    // T14 prefetch for tile kt+1 (drains at the ds_write at loop bottom)
    if (kt + 1 < NT) {
      const unsigned short* kp = kbase + (size_t)(kv0 + KVB + skv) * D_ + kc * 8;
      const unsigned short* vp = vbase + (size_t)(kv0 + KVB + skv) * D_ + kc * 8;
      kr0 = *(const uint4*)kp; kr1 = *(const uint4*)(kp + 8);
      vr0 = *(const uint4*)vp; vr1 = *(const uint4*)(vp + 8);
    }

    // ---- S^T = K @ Q^T ----
    floatx16 s0, s1;
#pragma unroll
    for (int r = 0; r < 16; r++) { s0[r] = 0.f; s1[r] = 0.f; }
    __builtin_amdgcn_s_setprio(1);
#pragma unroll
    for (int ks = 0; ks < 4; ks++) {
      bf16x8 ak0 = __builtin_bit_cast(bf16x8, *(const uint4*)&Ks[cur][q5][(((ks << 1) | h5) ^ cshift) * 8]);
      bf16x8 ak1 = __builtin_bit_cast(bf16x8, *(const uint4*)&Ks[cur][32 + q5][(((ks << 1) | h5) ^ cshift) * 8]);
      s0 = __builtin_amdgcn_mfma_f32_32x32x16_bf16(ak0, bq[ks], s0, 0, 0, 0);
      s1 = __builtin_amdgcn_mfma_f32_32x32x16_bf16(ak1, bq[ks], s1, 0, 0, 0);
    }
    __builtin_amdgcn_s_setprio(0);

    const float csc = 0.180336880111120419f;  // 0.125 * log2(e)
    if (TFlag[kt]) {
#pragma unroll
      for (int r = 0; r < 16; r++) { s0[r] *= csc; s1[r] *= csc; }
    } else {
      // slow path (partial mask): direct global mask reads, L2-resident
#pragma unroll
      for (int r = 0; r < 16; r++) {
        const int kvl = (r & 3) + 8 * (r >> 2) + 4 * h5;
        s0[r] = s0[r] * csc + (mp[kv0 + kvl] ? 0.f : -1e30f);
        s1[r] = s1[r] * csc + (mp[kv0 + 32 + kvl] ? 0.f : -1e30f);
      }
    }

    // ---- in-register row softmax + defer-max (T13, THR=8 in log2 domain) ----
    float v8[8];
#pragma unroll
    for (int i = 0; i < 8; i++)
      v8[i] = fmaxf(fmaxf(s0[i], s0[i + 8]), fmaxf(s1[i], s1[i + 8]));
    float rmax = fmaxf(fmaxf(fmaxf(v8[0], v8[4]), fmaxf(v8[1], v8[5])),
                       fmaxf(fmaxf(v8[2], v8[6]), fmaxf(v8[3], v8[7])));
    rmax = fmaxf(rmax, __shfl_xor(rmax, 32, 64));
    if (!__all(rmax <= m_ + 8.f)) {
      const float mn = fmaxf(fmaxf(m_, rmax), -1e29f);
      const float corr = exp2f(m_ - mn);
      m_ = mn;
      l_ *= corr;
#pragma unroll
      for (int r = 0; r < 16; r++) { o0[r] *= corr; o1[r] *= corr; }
    }
#pragma unroll
    for (int r = 0; r < 16; r++) {
      s0[r] = exp2f(s0[r] - m_);
      s1[r] = exp2f(s1[r] - m_);
    }
    float a8[8];
#pragma unroll
    for (int i = 0; i < 8; i++) a8[i] = (s0[i] + s0[i + 8]) + (s1[i] + s1[i + 8]);
    float lsum = ((a8[0] + a8[1]) + (a8[2] + a8[3])) + ((a8[4] + a8[5]) + (a8[6] + a8[7]));
    lsum += __shfl_xor(lsum, 32, 64);
    l_ += lsum;

    // ---- P^T fragments: cvt_pk + permlane32_swap (T12) ----
    unsigned int w[16];
#pragma unroll
    for (int a = 0; a < 8; a++) {
      w[a] = cvtpk_bf16(s0[2 * a], s0[2 * a + 1]);
      w[8 + a] = cvtpk_bf16(s1[2 * a], s1[2 * a + 1]);
    }
#pragma unroll
    for (int ks = 0; ks < 4; ks++) {
      asm("v_permlane32_swap_b32 %0, %1" : "+v"(w[4 * ks]), "+v"(w[4 * ks + 2]));
      asm("v_permlane32_swap_b32 %0, %1" : "+v"(w[4 * ks + 1]), "+v"(w[4 * ks + 3]));
    }

    // ---- O^T += V^T @ P^T ----
    __builtin_amdgcn_s_setprio(1);
#pragma unroll
    for (int ks = 0; ks < 4; ks++) {
      const bf16x8 pa = __builtin_bit_cast(bf16x8,
          make_uint4(w[4 * ks], w[4 * ks + 1], w[4 * ks + 2], w[4 * ks + 3]));
      bf16x8 av0 = __builtin_bit_cast(bf16x8, *(const uint4*)&Vt[cur][q5][(((ks << 1) | h5) ^ vsh0) * 8]);
      bf16x8 av1 = __builtin_bit_cast(bf16x8, *(const uint4*)&Vt[cur][32 + q5][(((ks << 1) | h5) ^ vsh1) * 8]);
      o0 = __builtin_amdgcn_mfma_f32_32x32x16_bf16(av0, pa, o0, 0, 0, 0);
      o1 = __builtin_amdgcn_mfma_f32_32x32x16_bf16(av1, pa, o1, 0, 0, 0);
    }
    __builtin_amdgcn_s_setprio(0);

    // ---- stage tile kt+1 into buf[cur^1] (after compute; loads have drained) ----
    if (kt + 1 < NT) {
      *(uint4*)&Ks[cur ^ 1][skv][((kc) ^ (skv & 7)) * 8] = kr0;
      *(uint4*)&Ks[cur ^ 1][skv][((kc + 1) ^ (skv & 7)) * 8] = kr1;
      union { uint4 u; unsigned short e[8]; } a0, a1;
      a0.u = vr0; a1.u = vr1;
#pragma unroll
      for (int e = 0; e < 8; e++) {
        const int cp0 = (((skv >> 3) ^ e ^ kc) << 3) | (skv & 7);
        const int cp1 = (((skv >> 3) ^ e ^ (kc + 1)) << 3) | (skv & 7);
        Vt[cur ^ 1][kc * 8 + e][cp0] = a0.e[e];
        Vt[cur ^ 1][kc * 8 + 8 + e][cp1] = a1.e[e];
      }
    }
    __syncthreads();  // single barrier per tile: publishes buf[cur^1], guards buf[cur] reuse
  }

  {
    const float inv = 1.f / l_;
    unsigned int ep[16];
#pragma unroll
    for (int a = 0; a < 8; a++) {
      ep[a] = cvtpk_bf16(o0[2 * a] * inv, o0[2 * a + 1] * inv);
      ep[8 + a] = cvtpk_bf16(o1[2 * a] * inv, o1[2 * a + 1] * inv);
    }
    unsigned short* crow = ctx + (bS + qb * QBLK + wv * 32 + q5) * D_ + hb;
#pragma unroll
    for (int dt = 0; dt < 2; dt++)
#pragma unroll
      for (int g4 = 0; g4 < 4; g4++)
        *(uint2*)(crow + dt * 32 + g4 * 8 + h5 * 4) =
            make_uint2(ep[dt * 8 + g4 * 2], ep[dt * 8 + g4 * 2 + 1]);
  }
}

// ---------------- LayerNorm over rows of 768 ----------------
template <bool OUT_BF16>
__global__ __launch_bounds__(256) void ln_kernel(const float* __restrict__ x,
                                                 const float* __restrict__ g,
                                                 const float* __restrict__ be,
                                                 void* __restrict__ outv) {
  __shared__ float red[4];
  const int t = threadIdx.x, lane = t & 63, wave = t >> 6;
  const size_t row = blockIdx.x;
  const float* xr = x + row * D_;
  float v0 = xr[t], v1 = xr[t + 256], v2 = xr[t + 512];
  float s = v0 + v1 + v2;
#pragma unroll
  for (int off = 32; off; off >>= 1) s += __shfl_xor(s, off, 64);
  if (lane == 0) red[wave] = s;
  __syncthreads();
  const float mu = (red[0] + red[1] + red[2] + red[3]) * (1.f / 768.f);
  __syncthreads();
  const float d0 = v0 - mu, d1 = v1 - mu, d2 = v2 - mu;
  float vs = d0 * d0 + d1 * d1 + d2 * d2;
#pragma unroll
  for (int off = 32; off; off >>= 1) vs += __shfl_xor(vs, off, 64);
  if (lane == 0) red[wave] = vs;
  __syncthreads();
  const float rs = rsqrtf((red[0] + red[1] + red[2] + red[3]) * (1.f / 768.f) + 1e-6f);
  const float r0v = d0 * rs * g[t] + be[t];
  const float r1v = d1 * rs * g[t + 256] + be[t + 256];
  const float r2v = d2 * rs * g[t + 512] + be[t + 512];
  if (OUT_BF16) {
    unsigned short* o = (unsigned short*)outv + row * D_;
    o[t] = f2bf(r0v); o[t + 256] = f2bf(r1v); o[t + 512] = f2bf(r2v);
  } else {
    float* o = (float*)outv + row * D_;
    o[t] = r0v; o[t + 256] = r1v; o[t + 512] = r2v;
  }
}

// ---------------- host launcher ----------------
extern "C" void kernel_launch(void* const* d_in, const int* in_sizes, int n_in,
                              void* d_out, int out_size, void* d_ws, size_t ws_size,
                              hipStream_t stream) {
  const float* xq = (const float*)d_in[0];
  const float* xk = (const float*)d_in[1];
  const float* xv = (const float*)d_in[2];
  const int* mask = (const int*)d_in[3];
  const float* wq = (const float*)d_in[4];
  const float* bq = (const float*)d_in[5];
  const float* wk = (const float*)d_in[6];
  const float* bk = (const float*)d_in[7];
  const float* wv = (const float*)d_in[8];
  const float* bv = (const float*)d_in[9];
  const float* wo = (const float*)d_in[10];
  const float* bo = (const float*)d_in[11];
  const float* w1 = (const float*)d_in[12];
  const float* b1 = (const float*)d_in[13];
  const float* w2 = (const float*)d_in[14];
  const float* b2 = (const float*)d_in[15];
  const float* g1 = (const float*)d_in[16];
  const float* be1 = (const float*)d_in[17];
  const float* g2 = (const float*)d_in[18];
  const float* be2 = (const float*)d_in[19];
  float* out = (float*)d_out;
  char* ws = (char*)d_ws;

  // workspace layout (bytes); high water 114819072 (known-safe)
  unsigned short* WQT = (unsigned short*)(ws + 0);
  unsigned short* WKT = (unsigned short*)(ws + 1179648);
  unsigned short* WVT = (unsigned short*)(ws + 2359296);
  unsigned short* WOT = (unsigned short*)(ws + 3538944);
  unsigned short* W1T = (unsigned short*)(ws + 4718592);
  unsigned short* W2T = (unsigned short*)(ws + 9437184);
  unsigned short* XQB = (unsigned short*)(ws + 14155776);
  unsigned short* XKB = (unsigned short*)(ws + 26738688);
  unsigned short* XVB = (unsigned short*)(ws + 39321600);
  unsigned short* QB = (unsigned short*)(ws + 51904512);
  unsigned short* KB = (unsigned short*)(ws + 64487424);
  unsigned short* VB = (unsigned short*)(ws + 77070336);
  unsigned short* CTXB = (unsigned short*)(ws + 14155776);  // alias XQB (dead post-QKV)
  float* X1PRE = (float*)(ws + 51904512);                   // alias QB+KB (dead post-flash)
  unsigned short* X1B = (unsigned short*)(ws + 77070336);   // alias VB (dead post-flash)
  unsigned short* HB = (unsigned short*)(ws + 14155776);    // alias CTXB region (dead)
  float* X2PRE = (float*)(ws + 89653248);

  wtrans<<<dim3(24, 24), 256, 0, stream>>>(wq, WQT, 768, 768);
  wtrans<<<dim3(24, 24), 256, 0, stream>>>(wk, WKT, 768, 768);
  wtrans<<<dim3(24, 24), 256, 0, stream>>>(wv, WVT, 768, 768);
  wtrans<<<dim3(24, 24), 256, 0, stream>>>(wo, WOT, 768, 768);
  wtrans<<<dim3(96, 24), 256, 0, stream>>>(w1, W1T, 768, 3072);
  wtrans<<<dim3(24, 96), 256, 0, stream>>>(w2, W2T, 3072, 768);

  cvt_bf16<<<3072, 256, 0, stream>>>(xq, XQB, 786432);
  cvt_bf16<<<3072, 256, 0, stream>>>(xk, XKB, 786432);
  cvt_bf16<<<3072, 256, 0, stream>>>(xv, XVB, 786432);

  gemm_lds<false, 0, true><<<dim3(6, 64), 256, 0, stream>>>(XQB, WQT, bq, nullptr, QB, 8192, 768, 768);
  gemm_lds<false, 0, true><<<dim3(6, 64), 256, 0, stream>>>(XKB, WKT, bk, nullptr, KB, 8192, 768, 768);
  gemm_lds<false, 0, true><<<dim3(6, 64), 256, 0, stream>>>(XVB, WVT, bv, nullptr, VB, 8192, 768, 768);

  flash_attn_v4<<<dim3(S_ / QBLK, H_, B_), 256, 0, stream>>>(QB, KB, VB, mask, CTXB);

  gemm_lds<false, 1, false><<<dim3(6, 64), 256, 0, stream>>>(CTXB, WOT, bo, xq, X1PRE, 8192, 768, 768);

  ln_kernel<true><<<8192, 256, 0, stream>>>(X1PRE, g1, be1, X1B);

  gemm_lds<true, 0, true><<<dim3(24, 64), 256, 0, stream>>>(X1B, W1T, b1, nullptr, HB, 8192, 3072, 768);

  gemm_lds<false, 2, false><<<dim3(6, 64), 256, 0, stream>>>(HB, W2T, b2, X1B, X2PRE, 8192, 768, 3072);

  ln_kernel<false><<<8192, 256, 0, stream>>>(X2PRE, g2, be2, out);
}

// Round 8
// 422.465 us; speedup vs baseline: 1.1178x; 1.1178x over previous
//
#include <hip/hip_runtime.h>
#include <stdint.h>

#define B_ 2
#define S_ 4096
#define D_ 768
#define H_ 12
#define F_ 3072
#define DK_ 64
#define QBLK 128
#define KVB 64
#define NT (S_ / KVB)

typedef __bf16 bf16x8 __attribute__((ext_vector_type(8)));
typedef float floatx4 __attribute__((ext_vector_type(4)));
typedef float floatx16 __attribute__((ext_vector_type(16)));

__device__ __forceinline__ float bf2f(unsigned short u) {
  unsigned int x = ((unsigned int)u) << 16;
  return __builtin_bit_cast(float, x);
}
__device__ __forceinline__ unsigned short f2bf(float f) {
  unsigned int x = __builtin_bit_cast(unsigned int, f);
  x += 0x7FFFu + ((x >> 16) & 1u);
  return (unsigned short)(x >> 16);
}
__device__ __forceinline__ unsigned int cvtpk_bf16(float lo, float hi) {
  unsigned int r;
  asm("v_cvt_pk_bf16_f32 %0, %1, %2" : "=v"(r) : "v"(lo), "v"(hi));
  return r;
}

// ---------------- weight transpose + cvt: w[K][N] f32 -> wt[N][K] bf16 ----------------
__device__ __forceinline__ void wtrans_core(const float* __restrict__ w,
                                            unsigned short* __restrict__ wt,
                                            int K, int N) {
  __shared__ float tile[32][33];
  const int n0 = blockIdx.x * 32, k0 = blockIdx.y * 32;
  const int tx = threadIdx.x & 31, ty8 = threadIdx.x >> 5;
#pragma unroll
  for (int r = 0; r < 4; r++)
    tile[ty8 + r * 8][tx] = w[(size_t)(k0 + ty8 + r * 8) * N + n0 + tx];
  __syncthreads();
#pragma unroll
  for (int r = 0; r < 4; r++)
    wt[(size_t)(n0 + ty8 + r * 8) * K + k0 + tx] = f2bf(tile[tx][ty8 + r * 8]);
}

__global__ __launch_bounds__(256) void wtrans(const float* __restrict__ w,
                                              unsigned short* __restrict__ wt,
                                              int K, int N) {
  wtrans_core(w, wt, K, N);
}

// z-batched: four 768x768 weights -> contiguous outputs
__global__ __launch_bounds__(256) void wtrans4(const float* __restrict__ w0,
                                               const float* __restrict__ w1,
                                               const float* __restrict__ w2,
                                               const float* __restrict__ w3,
                                               unsigned short* __restrict__ wtbase) {
  const int z = blockIdx.z;
  const float* w = (z == 0) ? w0 : (z == 1) ? w1 : (z == 2) ? w2 : w3;
  wtrans_core(w, wtbase + (size_t)z * 589824, 768, 768);
}

// ---------------- f32 -> bf16 bulk convert, z-batched over 3 inputs ----------------
__global__ __launch_bounds__(256) void cvt_bf16_3(const float* __restrict__ x0,
                                                  const float* __restrict__ x1,
                                                  const float* __restrict__ x2,
                                                  unsigned short* __restrict__ ybase, int n8) {
  const int z = blockIdx.z;
  const float* x = (z == 0) ? x0 : (z == 1) ? x1 : x2;
  unsigned short* y = ybase + (size_t)z * 6291456;
  const int i = blockIdx.x * 256 + threadIdx.x;
  if (i >= n8) return;
  const float4 a = ((const float4*)x)[2 * i];
  const float4 b = ((const float4*)x)[2 * i + 1];
  uint4 o;
  o.x = (unsigned int)f2bf(a.x) | ((unsigned int)f2bf(a.y) << 16);
  o.y = (unsigned int)f2bf(a.z) | ((unsigned int)f2bf(a.w) << 16);
  o.z = (unsigned int)f2bf(b.x) | ((unsigned int)f2bf(b.y) << 16);
  o.w = (unsigned int)f2bf(b.z) | ((unsigned int)f2bf(b.w) << 16);
  ((uint4*)y)[i] = o;
}

// ---------------- GEMM core (m97 structure, BK=64) ----------------
// RESID_MODE: 0 none, 1 f32, 2 bf16.
template <bool RELU, int RESID_MODE, bool OUT_BF16>
__device__ __forceinline__ void gemm_core(
    const unsigned short* __restrict__ A, const unsigned short* __restrict__ Bt,
    const float* __restrict__ bias, const void* __restrict__ residv,
    void* __restrict__ outv, int M, int N, int K) {
  __shared__ __align__(16) unsigned short As[128 * 64];
  __shared__ __align__(16) unsigned short Bs[128 * 64];
  int bx = blockIdx.x, by = blockIdx.y;
  {
    const int gx = gridDim.x;
    const int nwg = gx * gridDim.y;       // all grids divisible by 8
    const int flat = by * gx + bx;
    const int wg = (flat & 7) * (nwg >> 3) + (flat >> 3);
    bx = wg % gx; by = wg / gx;
  }
  const int t = threadIdx.x;
  const int lane = t & 63, wave = t >> 6;
  const int m0 = by * 128, n0 = bx * 128;
  const int wm = (wave >> 1) * 64, wn = (wave & 1) * 64;
  const int rl = lane & 15, kl = (lane >> 4) * 8;
  const int lrow = lane >> 3, lcol = (lane & 7) * 8;

  floatx4 zf = {0.f, 0.f, 0.f, 0.f};
  floatx4 acc[4][4];
#pragma unroll
  for (int i = 0; i < 4; i++)
#pragma unroll
    for (int j = 0; j < 4; j++) acc[i][j] = zf;

  const unsigned short* Ab = A + (size_t)(m0 + wave * 32 + lrow) * K + lcol;
  const unsigned short* Bb = Bt + (size_t)(n0 + wave * 32 + lrow) * K + lcol;
  unsigned short* AsW = As + wave * 2048;
  unsigned short* BsW = Bs + wave * 2048;

  for (int k0 = 0; k0 < K; k0 += 64) {
    __syncthreads();
#pragma unroll
    for (int ld = 0; ld < 4; ld++) {
      __builtin_amdgcn_global_load_lds(Ab + k0 + (size_t)(ld * 8) * K, AsW + ld * 512, 16, 0, 0);
      __builtin_amdgcn_global_load_lds(Bb + k0 + (size_t)(ld * 8) * K, BsW + ld * 512, 16, 0, 0);
    }
    __syncthreads();
#pragma unroll
    for (int ks = 0; ks < 2; ks++) {
      bf16x8 af[4], bff[4];
#pragma unroll
      for (int i = 0; i < 4; i++)
        af[i] = __builtin_bit_cast(bf16x8, *(const uint4*)&As[(wm + i * 16 + rl) * 64 + ks * 32 + kl]);
#pragma unroll
      for (int j = 0; j < 4; j++)
        bff[j] = __builtin_bit_cast(bf16x8, *(const uint4*)&Bs[(wn + j * 16 + rl) * 64 + ks * 32 + kl]);
#pragma unroll
      for (int i = 0; i < 4; i++)
#pragma unroll
        for (int j = 0; j < 4; j++)
          acc[i][j] = __builtin_amdgcn_mfma_f32_16x16x32_bf16(af[i], bff[j], acc[i][j], 0, 0, 0);
    }
  }

  const int r0 = (lane >> 4) * 4;
#pragma unroll
  for (int i = 0; i < 4; i++) {
#pragma unroll
    for (int j = 0; j < 4; j++) {
      const int col = n0 + wn + j * 16 + rl;
      const float bv = bias[col];
#pragma unroll
      for (int r = 0; r < 4; r++) {
        const int row = m0 + wm + i * 16 + r0 + r;
        float v = acc[i][j][r] + bv;
        if (RESID_MODE == 1) v += ((const float*)residv)[(size_t)row * N + col];
        if (RESID_MODE == 2) v += bf2f(((const unsigned short*)residv)[(size_t)row * N + col]);
        if (RELU) v = v > 0.f ? v : 0.f;
        if (OUT_BF16)
          ((unsigned short*)outv)[(size_t)row * N + col] = f2bf(v);
        else
          ((float*)outv)[(size_t)row * N + col] = v;
      }
    }
  }
}

template <bool RELU, int RESID_MODE, bool OUT_BF16>
__global__ __launch_bounds__(256, 2) void gemm_lds(
    const unsigned short* __restrict__ A, const unsigned short* __restrict__ Bt,
    const float* __restrict__ bias, const void* __restrict__ residv,
    void* __restrict__ outv, int M, int N, int K) {
  gemm_core<RELU, RESID_MODE, OUT_BF16>(A, Bt, bias, residv, outv, M, N, K);
}

// z-batched QKV projection: A/Bt/out contiguous slices, bias selected per z
__global__ __launch_bounds__(256, 2) void gemm_qkv(
    const unsigned short* __restrict__ Abase, const unsigned short* __restrict__ Btbase,
    const float* __restrict__ b0, const float* __restrict__ b1, const float* __restrict__ b2,
    unsigned short* __restrict__ outbase) {
  const int z = blockIdx.z;
  const float* bp = (z == 0) ? b0 : (z == 1) ? b1 : b2;
  gemm_core<false, 0, true>(Abase + (size_t)z * 6291456, Btbase + (size_t)z * 589824,
                            bp, nullptr, outbase + (size_t)z * 6291456, 8192, 768, 768);
}

// ---------------- flash attention v5: no-max softmax (clamped), dbuf single-barrier ----------------
// 4 waves x 32 q rows; swapped QK^T (lane owns a q-row), in-register softmax (T12),
// double-buffered K/Vt LDS, one barrier per tile, T14 prefetch.
// Softmax WITHOUT online max: p = exp2(clamp(s*csc + maskbias, +-88)); out = (sum p V)/(sum p).
// Mathematically identical to max-subtracted softmax when nothing overflows; clamp guarantees
// no overflow for any |s*csc| (p <= 2^88, l <= 4096*2^88 << f32 max; masked -> 2^-88 ~= 0).
__global__ __launch_bounds__(256, 3) void flash_attn_v5(
    const unsigned short* __restrict__ qg, const unsigned short* __restrict__ kg,
    const unsigned short* __restrict__ vg, const int* __restrict__ maskg,
    unsigned short* __restrict__ ctx) {
  __shared__ __align__(16) unsigned short Ks[2][64][64];
  __shared__ __align__(16) unsigned short Vt[2][64][64];
  __shared__ unsigned char TFlag[NT];

  const int t = threadIdx.x;
  const int L = t & 63, wv = t >> 6;
  const int q5 = L & 31, h5 = L >> 5;
  const int qb = blockIdx.x, h = blockIdx.y, b = blockIdx.z;
  const size_t bS = (size_t)b * S_;
  const int hb = h * DK_;
  const unsigned short* kbase = kg + bS * D_ + hb;
  const unsigned short* vbase = vg + bS * D_ + hb;
  const int* mp = maskg + bS;

  for (int tt = wv; tt < NT; tt += 4) {
    const int mv = mp[tt * KVB + L];
    const unsigned long long bal = __ballot(mv != 0);
    if (L == 0) TFlag[tt] = (bal == ~0ull) ? 1 : 0;
  }

  bf16x8 bq[4];
  {
    const unsigned short* qp = qg + (bS + qb * QBLK + wv * 32 + q5) * D_ + hb + h5 * 8;
#pragma unroll
    for (int ks = 0; ks < 4; ks++)
      bq[ks] = __builtin_bit_cast(bf16x8, *(const uint4*)(qp + ks * 16));
  }

  floatx16 o0, o1;
#pragma unroll
  for (int r = 0; r < 16; r++) { o0[r] = 0.f; o1[r] = 0.f; }
  float l_ = 0.f;

  const int skv = t >> 2, kc = (t & 3) * 2;
  const int cshift = q5 & 7;
  const int vsh0 = (q5 & 7) ^ (q5 >> 3);
  const int vsh1 = vsh0 ^ 4;

  uint4 kr0, kr1, vr0, vr1;
  {
    const unsigned short* kp = kbase + (size_t)skv * D_ + kc * 8;
    const unsigned short* vp = vbase + (size_t)skv * D_ + kc * 8;
    kr0 = *(const uint4*)kp; kr1 = *(const uint4*)(kp + 8);
    vr0 = *(const uint4*)vp; vr1 = *(const uint4*)(vp + 8);
    *(uint4*)&Ks[0][skv][((kc) ^ (skv & 7)) * 8] = kr0;
    *(uint4*)&Ks[0][skv][((kc + 1) ^ (skv & 7)) * 8] = kr1;
    union { uint4 u; unsigned short e[8]; } a0, a1;
    a0.u = vr0; a1.u = vr1;
#pragma unroll
    for (int e = 0; e < 8; e++) {
      const int cp0 = (((skv >> 3) ^ e ^ kc) << 3) | (skv & 7);
      const int cp1 = (((skv >> 3) ^ e ^ (kc + 1)) << 3) | (skv & 7);
      Vt[0][kc * 8 + e][cp0] = a0.e[e];
      Vt[0][kc * 8 + 8 + e][cp1] = a1.e[e];
    }
  }
  __syncthreads();

  for (int kt = 0; kt < NT; kt++) {
    const int cur = kt & 1;
    const int kv0 = kt * KVB;
    if (kt + 1 < NT) {  // T14 prefetch
      const unsigned short* kp = kbase + (size_t)(kv0 + KVB + skv) * D_ + kc * 8;
      const unsigned short* vp = vbase + (size_t)(kv0 + KVB + skv) * D_ + kc * 8;
      kr0 = *(const uint4*)kp; kr1 = *(const uint4*)(kp + 8);
      vr0 = *(const uint4*)vp; vr1 = *(const uint4*)(vp + 8);
    }

    // ---- S^T = K @ Q^T ----
    floatx16 s0, s1;
#pragma unroll
    for (int r = 0; r < 16; r++) { s0[r] = 0.f; s1[r] = 0.f; }
    __builtin_amdgcn_s_setprio(1);
#pragma unroll
    for (int ks = 0; ks < 4; ks++) {
      bf16x8 ak0 = __builtin_bit_cast(bf16x8, *(const uint4*)&Ks[cur][q5][(((ks << 1) | h5) ^ cshift) * 8]);
      bf16x8 ak1 = __builtin_bit_cast(bf16x8, *(const uint4*)&Ks[cur][32 + q5][(((ks << 1) | h5) ^ cshift) * 8]);
      s0 = __builtin_amdgcn_mfma_f32_32x32x16_bf16(ak0, bq[ks], s0, 0, 0, 0);
      s1 = __builtin_amdgcn_mfma_f32_32x32x16_bf16(ak1, bq[ks], s1, 0, 0, 0);
    }
    __builtin_amdgcn_s_setprio(0);

    // ---- scale (+mask bias) + clamp, then exp2 directly (no max pass) ----
    const float csc = 0.180336880111120419f;  // 0.125 * log2(e)
    if (TFlag[kt]) {
#pragma unroll
      for (int r = 0; r < 16; r++) {
        s0[r] = fminf(fmaxf(s0[r] * csc, -88.f), 88.f);
        s1[r] = fminf(fmaxf(s1[r] * csc, -88.f), 88.f);
      }
    } else {
#pragma unroll
      for (int r = 0; r < 16; r++) {
        const int kvl = (r & 3) + 8 * (r >> 2) + 4 * h5;
        s0[r] = fminf(fmaxf(s0[r] * csc + (mp[kv0 + kvl] ? 0.f : -1e30f), -88.f), 88.f);
        s1[r] = fminf(fmaxf(s1[r] * csc + (mp[kv0 + 32 + kvl] ? 0.f : -1e30f), -88.f), 88.f);
      }
    }
#pragma unroll
    for (int r = 0; r < 16; r++) {
      s0[r] = exp2f(s0[r]);
      s1[r] = exp2f(s1[r]);
    }
    float a8[8];
#pragma unroll
    for (int i = 0; i < 8; i++) a8[i] = (s0[i] + s0[i + 8]) + (s1[i] + s1[i + 8]);
    float lsum = ((a8[0] + a8[1]) + (a8[2] + a8[3])) + ((a8[4] + a8[5]) + (a8[6] + a8[7]));
    lsum += __shfl_xor(lsum, 32, 64);
    l_ += lsum;

    // ---- P^T fragments: cvt_pk + permlane32_swap (T12) ----
    unsigned int w[16];
#pragma unroll
    for (int a = 0; a < 8; a++) {
      w[a] = cvtpk_bf16(s0[2 * a], s0[2 * a + 1]);
      w[8 + a] = cvtpk_bf16(s1[2 * a], s1[2 * a + 1]);
    }
#pragma unroll
    for (int ks = 0; ks < 4; ks++) {
      asm("v_permlane32_swap_b32 %0, %1" : "+v"(w[4 * ks]), "+v"(w[4 * ks + 2]));
      asm("v_permlane32_swap_b32 %0, %1" : "+v"(w[4 * ks + 1]), "+v"(w[4 * ks + 3]));
    }

    // ---- O^T += V^T @ P^T ----
    __builtin_amdgcn_s_setprio(1);
#pragma unroll
    for (int ks = 0; ks < 4; ks++) {
      const bf16x8 pa = __builtin_bit_cast(bf16x8,
          make_uint4(w[4 * ks], w[4 * ks + 1], w[4 * ks + 2], w[4 * ks + 3]));
      bf16x8 av0 = __builtin_bit_cast(bf16x8, *(const uint4*)&Vt[cur][q5][(((ks << 1) | h5) ^ vsh0) * 8]);
      bf16x8 av1 = __builtin_bit_cast(bf16x8, *(const uint4*)&Vt[cur][32 + q5][(((ks << 1) | h5) ^ vsh1) * 8]);
      o0 = __builtin_amdgcn_mfma_f32_32x32x16_bf16(av0, pa, o0, 0, 0, 0);
      o1 = __builtin_amdgcn_mfma_f32_32x32x16_bf16(av1, pa, o1, 0, 0, 0);
    }
    __builtin_amdgcn_s_setprio(0);

    // ---- stage tile kt+1 into buf[cur^1] ----
    if (kt + 1 < NT) {
      *(uint4*)&Ks[cur ^ 1][skv][((kc) ^ (skv & 7)) * 8] = kr0;
      *(uint4*)&Ks[cur ^ 1][skv][((kc + 1) ^ (skv & 7)) * 8] = kr1;
      union { uint4 u; unsigned short e[8]; } a0, a1;
      a0.u = vr0; a1.u = vr1;
#pragma unroll
      for (int e = 0; e < 8; e++) {
        const int cp0 = (((skv >> 3) ^ e ^ kc) << 3) | (skv & 7);
        const int cp1 = (((skv >> 3) ^ e ^ (kc + 1)) << 3) | (skv & 7);
        Vt[cur ^ 1][kc * 8 + e][cp0] = a0.e[e];
        Vt[cur ^ 1][kc * 8 + 8 + e][cp1] = a1.e[e];
      }
    }
    __syncthreads();  // publishes buf[cur^1], guards buf[cur] reuse
  }

  {
    const float inv = 1.f / l_;
    unsigned int ep[16];
#pragma unroll
    for (int a = 0; a < 8; a++) {
      ep[a] = cvtpk_bf16(o0[2 * a] * inv, o0[2 * a + 1] * inv);
      ep[8 + a] = cvtpk_bf16(o1[2 * a] * inv, o1[2 * a + 1] * inv);
    }
    unsigned short* crow = ctx + (bS + qb * QBLK + wv * 32 + q5) * D_ + hb;
#pragma unroll
    for (int dt = 0; dt < 2; dt++)
#pragma unroll
      for (int g4 = 0; g4 < 4; g4++)
        *(uint2*)(crow + dt * 32 + g4 * 8 + h5 * 4) =
            make_uint2(ep[dt * 8 + g4 * 2], ep[dt * 8 + g4 * 2 + 1]);
  }
}

// ---------------- LayerNorm over rows of 768 ----------------
template <bool OUT_BF16>
__global__ __launch_bounds__(256) void ln_kernel(const float* __restrict__ x,
                                                 const float* __restrict__ g,
                                                 const float* __restrict__ be,
                                                 void* __restrict__ outv) {
  __shared__ float red[4];
  const int t = threadIdx.x, lane = t & 63, wave = t >> 6;
  const size_t row = blockIdx.x;
  const float* xr = x + row * D_;
  float v0 = xr[t], v1 = xr[t + 256], v2 = xr[t + 512];
  float s = v0 + v1 + v2;
#pragma unroll
  for (int off = 32; off; off >>= 1) s += __shfl_xor(s, off, 64);
  if (lane == 0) red[wave] = s;
  __syncthreads();
  const float mu = (red[0] + red[1] + red[2] + red[3]) * (1.f / 768.f);
  __syncthreads();
  const float d0 = v0 - mu, d1 = v1 - mu, d2 = v2 - mu;
  float vs = d0 * d0 + d1 * d1 + d2 * d2;
#pragma unroll
  for (int off = 32; off; off >>= 1) vs += __shfl_xor(vs, off, 64);
  if (lane == 0) red[wave] = vs;
  __syncthreads();
  const float rs = rsqrtf((red[0] + red[1] + red[2] + red[3]) * (1.f / 768.f) + 1e-6f);
  const float r0v = d0 * rs * g[t] + be[t];
  const float r1v = d1 * rs * g[t + 256] + be[t + 256];
  const float r2v = d2 * rs * g[t + 512] + be[t + 512];
  if (OUT_BF16) {
    unsigned short* o = (unsigned short*)outv + row * D_;
    o[t] = f2bf(r0v); o[t + 256] = f2bf(r1v); o[t + 512] = f2bf(r2v);
  } else {
    float* o = (float*)outv + row * D_;
    o[t] = r0v; o[t + 256] = r1v; o[t + 512] = r2v;
  }
}

// ---------------- host launcher ----------------
extern "C" void kernel_launch(void* const* d_in, const int* in_sizes, int n_in,
                              void* d_out, int out_size, void* d_ws, size_t ws_size,
                              hipStream_t stream) {
  const float* xq = (const float*)d_in[0];
  const float* xk = (const float*)d_in[1];
  const float* xv = (const float*)d_in[2];
  const int* mask = (const int*)d_in[3];
  const float* wq = (const float*)d_in[4];
  const float* bq = (const float*)d_in[5];
  const float* wk = (const float*)d_in[6];
  const float* bk = (const float*)d_in[7];
  const float* wv = (const float*)d_in[8];
  const float* bv = (const float*)d_in[9];
  const float* wo = (const float*)d_in[10];
  const float* bo = (const float*)d_in[11];
  const float* w1 = (const float*)d_in[12];
  const float* b1 = (const float*)d_in[13];
  const float* w2 = (const float*)d_in[14];
  const float* b2 = (const float*)d_in[15];
  const float* g1 = (const float*)d_in[16];
  const float* be1 = (const float*)d_in[17];
  const float* g2 = (const float*)d_in[18];
  const float* be2 = (const float*)d_in[19];
  float* out = (float*)d_out;
  char* ws = (char*)d_ws;

  // workspace layout (bytes); high water 114819072 (known-safe)
  unsigned short* WQT = (unsigned short*)(ws + 0);          // WQT..WOT contiguous (wtrans4)
  unsigned short* W1T = (unsigned short*)(ws + 4718592);
  unsigned short* W2T = (unsigned short*)(ws + 9437184);
  unsigned short* XQB = (unsigned short*)(ws + 14155776);   // XQB/XKB/XVB contiguous
  unsigned short* QB = (unsigned short*)(ws + 51904512);    // QB/KB/VB contiguous
  unsigned short* KB = (unsigned short*)(ws + 64487424);
  unsigned short* VB = (unsigned short*)(ws + 77070336);
  unsigned short* CTXB = (unsigned short*)(ws + 14155776);  // alias XQB (dead post-QKV)
  float* X1PRE = (float*)(ws + 51904512);                   // alias QB+KB (dead post-flash)
  unsigned short* X1B = (unsigned short*)(ws + 77070336);   // alias VB (dead post-flash)
  unsigned short* HB = (unsigned short*)(ws + 14155776);    // alias CTXB region (dead)
  float* X2PRE = (float*)(ws + 89653248);
  unsigned short* WOT = WQT + 3 * 589824;

  wtrans4<<<dim3(24, 24, 4), 256, 0, stream>>>(wq, wk, wv, wo, WQT);
  wtrans<<<dim3(96, 24), 256, 0, stream>>>(w1, W1T, 768, 3072);
  wtrans<<<dim3(24, 96), 256, 0, stream>>>(w2, W2T, 3072, 768);

  cvt_bf16_3<<<dim3(3072, 1, 3), 256, 0, stream>>>(xq, xk, xv, XQB, 786432);

  gemm_qkv<<<dim3(6, 64, 3), 256, 0, stream>>>(XQB, WQT, bq, bk, bv, QB);

  flash_attn_v5<<<dim3(S_ / QBLK, H_, B_), 256, 0, stream>>>(QB, KB, VB, mask, CTXB);

  gemm_lds<false, 1, false><<<dim3(6, 64), 256, 0, stream>>>(CTXB, WOT, bo, xq, X1PRE, 8192, 768, 768);

  ln_kernel<true><<<8192, 256, 0, stream>>>(X1PRE, g1, be1, X1B);

  gemm_lds<true, 0, true><<<dim3(24, 64), 256, 0, stream>>>(X1B, W1T, b1, nullptr, HB, 8192, 3072, 768);

  gemm_lds<false, 2, false><<<dim3(6, 64), 256, 0, stream>>>(HB, W2T, b2, X1B, X2PRE, 8192, 768, 3072);

  ln_kernel<false><<<8192, 256, 0, stream>>>(X2PRE, g2, be2, out);
}

// Round 9
// 413.671 us; speedup vs baseline: 1.1416x; 1.0213x over previous
//
#include <hip/hip_runtime.h>
#include <stdint.h>

#define B_ 2
#define S_ 4096
#define D_ 768
#define H_ 12
#define F_ 3072
#define DK_ 64
#define QBLK 128
#define KVB 64
#define NT (S_ / KVB)

typedef __bf16 bf16x8 __attribute__((ext_vector_type(8)));
typedef float floatx4 __attribute__((ext_vector_type(4)));
typedef float floatx16 __attribute__((ext_vector_type(16)));

__device__ __forceinline__ float bf2f(unsigned short u) {
  unsigned int x = ((unsigned int)u) << 16;
  return __builtin_bit_cast(float, x);
}
__device__ __forceinline__ unsigned short f2bf(float f) {
  unsigned int x = __builtin_bit_cast(unsigned int, f);
  x += 0x7FFFu + ((x >> 16) & 1u);
  return (unsigned short)(x >> 16);
}
__device__ __forceinline__ unsigned int cvtpk_bf16(float lo, float hi) {
  unsigned int r;
  asm("v_cvt_pk_bf16_f32 %0, %1, %2" : "=v"(r) : "v"(lo), "v"(hi));
  return r;
}

// ---------------- weight transpose + cvt: w[K][N] f32 -> wt[N][K] bf16 ----------------
__device__ __forceinline__ void wtrans_core(const float* __restrict__ w,
                                            unsigned short* __restrict__ wt,
                                            int K, int N) {
  __shared__ float tile[32][33];
  const int n0 = blockIdx.x * 32, k0 = blockIdx.y * 32;
  const int tx = threadIdx.x & 31, ty8 = threadIdx.x >> 5;
#pragma unroll
  for (int r = 0; r < 4; r++)
    tile[ty8 + r * 8][tx] = w[(size_t)(k0 + ty8 + r * 8) * N + n0 + tx];
  __syncthreads();
#pragma unroll
  for (int r = 0; r < 4; r++)
    wt[(size_t)(n0 + ty8 + r * 8) * K + k0 + tx] = f2bf(tile[tx][ty8 + r * 8]);
}

__global__ __launch_bounds__(256) void wtrans(const float* __restrict__ w,
                                              unsigned short* __restrict__ wt,
                                              int K, int N) {
  wtrans_core(w, wt, K, N);
}

__global__ __launch_bounds__(256) void wtrans4(const float* __restrict__ w0,
                                               const float* __restrict__ w1,
                                               const float* __restrict__ w2,
                                               const float* __restrict__ w3,
                                               unsigned short* __restrict__ wtbase) {
  const int z = blockIdx.z;
  const float* w = (z == 0) ? w0 : (z == 1) ? w1 : (z == 2) ? w2 : w3;
  wtrans_core(w, wtbase + (size_t)z * 589824, 768, 768);
}

// ---------------- f32 -> bf16 bulk convert, z-batched over 3 inputs ----------------
__global__ __launch_bounds__(256) void cvt_bf16_3(const float* __restrict__ x0,
                                                  const float* __restrict__ x1,
                                                  const float* __restrict__ x2,
                                                  unsigned short* __restrict__ ybase, int n8) {
  const int z = blockIdx.z;
  const float* x = (z == 0) ? x0 : (z == 1) ? x1 : x2;
  unsigned short* y = ybase + (size_t)z * 6291456;
  const int i = blockIdx.x * 256 + threadIdx.x;
  if (i >= n8) return;
  const float4 a = ((const float4*)x)[2 * i];
  const float4 b = ((const float4*)x)[2 * i + 1];
  uint4 o;
  o.x = (unsigned int)f2bf(a.x) | ((unsigned int)f2bf(a.y) << 16);
  o.y = (unsigned int)f2bf(a.z) | ((unsigned int)f2bf(a.w) << 16);
  o.z = (unsigned int)f2bf(b.x) | ((unsigned int)f2bf(b.y) << 16);
  o.w = (unsigned int)f2bf(b.z) | ((unsigned int)f2bf(b.w) << 16);
  ((uint4*)y)[i] = o;
}

// ---------------- GEMM core (m97 structure, BK=64) ----------------
// RESID_MODE: 0 none, 1 f32, 2 bf16. If vtout != nullptr: write transposed
// VT[b][col][s] (b = row>>12, s = row&4095) instead of row-major out.
template <bool RELU, int RESID_MODE, bool OUT_BF16>
__device__ __forceinline__ void gemm_core(
    const unsigned short* __restrict__ A, const unsigned short* __restrict__ Bt,
    const float* __restrict__ bias, const void* __restrict__ residv,
    void* __restrict__ outv, unsigned short* __restrict__ vtout,
    int M, int N, int K) {
  __shared__ __align__(16) unsigned short As[128 * 64];
  __shared__ __align__(16) unsigned short Bs[128 * 64];
  int bx = blockIdx.x, by = blockIdx.y;
  {
    const int gx = gridDim.x;
    const int nwg = gx * gridDim.y;       // all grids divisible by 8
    const int flat = by * gx + bx;
    const int wg = (flat & 7) * (nwg >> 3) + (flat >> 3);
    bx = wg % gx; by = wg / gx;
  }
  const int t = threadIdx.x;
  const int lane = t & 63, wave = t >> 6;
  const int m0 = by * 128, n0 = bx * 128;
  const int wm = (wave >> 1) * 64, wn = (wave & 1) * 64;
  const int rl = lane & 15, kl = (lane >> 4) * 8;
  const int lrow = lane >> 3, lcol = (lane & 7) * 8;

  floatx4 zf = {0.f, 0.f, 0.f, 0.f};
  floatx4 acc[4][4];
#pragma unroll
  for (int i = 0; i < 4; i++)
#pragma unroll
    for (int j = 0; j < 4; j++) acc[i][j] = zf;

  const unsigned short* Ab = A + (size_t)(m0 + wave * 32 + lrow) * K + lcol;
  const unsigned short* Bb = Bt + (size_t)(n0 + wave * 32 + lrow) * K + lcol;
  unsigned short* AsW = As + wave * 2048;
  unsigned short* BsW = Bs + wave * 2048;

  for (int k0 = 0; k0 < K; k0 += 64) {
    __syncthreads();
#pragma unroll
    for (int ld = 0; ld < 4; ld++) {
      __builtin_amdgcn_global_load_lds(Ab + k0 + (size_t)(ld * 8) * K, AsW + ld * 512, 16, 0, 0);
      __builtin_amdgcn_global_load_lds(Bb + k0 + (size_t)(ld * 8) * K, BsW + ld * 512, 16, 0, 0);
    }
    __syncthreads();
#pragma unroll
    for (int ks = 0; ks < 2; ks++) {
      bf16x8 af[4], bff[4];
#pragma unroll
      for (int i = 0; i < 4; i++)
        af[i] = __builtin_bit_cast(bf16x8, *(const uint4*)&As[(wm + i * 16 + rl) * 64 + ks * 32 + kl]);
#pragma unroll
      for (int j = 0; j < 4; j++)
        bff[j] = __builtin_bit_cast(bf16x8, *(const uint4*)&Bs[(wn + j * 16 + rl) * 64 + ks * 32 + kl]);
#pragma unroll
      for (int i = 0; i < 4; i++)
#pragma unroll
        for (int j = 0; j < 4; j++)
          acc[i][j] = __builtin_amdgcn_mfma_f32_16x16x32_bf16(af[i], bff[j], acc[i][j], 0, 0, 0);
    }
  }

  const int r0 = (lane >> 4) * 4;
  if (vtout) {
    // transposed write: VT[(b*768 + col)*4096 + s], 4 consecutive rows pack to uint2
#pragma unroll
    for (int i = 0; i < 4; i++) {
#pragma unroll
      for (int j = 0; j < 4; j++) {
        const int col = n0 + wn + j * 16 + rl;
        const float bv = bias[col];
        const int rowb = m0 + wm + i * 16 + r0;
        const int bb = rowb >> 12, s = rowb & 4095;
        unsigned short e[4];
#pragma unroll
        for (int r = 0; r < 4; r++) e[r] = f2bf(acc[i][j][r] + bv);
        *(uint2*)&vtout[((size_t)bb * D_ + col) * 4096 + s] =
            make_uint2((unsigned int)e[0] | ((unsigned int)e[1] << 16),
                       (unsigned int)e[2] | ((unsigned int)e[3] << 16));
      }
    }
    return;
  }
#pragma unroll
  for (int i = 0; i < 4; i++) {
#pragma unroll
    for (int j = 0; j < 4; j++) {
      const int col = n0 + wn + j * 16 + rl;
      const float bv = bias[col];
#pragma unroll
      for (int r = 0; r < 4; r++) {
        const int row = m0 + wm + i * 16 + r0 + r;
        float v = acc[i][j][r] + bv;
        if (RESID_MODE == 1) v += ((const float*)residv)[(size_t)row * N + col];
        if (RESID_MODE == 2) v += bf2f(((const unsigned short*)residv)[(size_t)row * N + col]);
        if (RELU) v = v > 0.f ? v : 0.f;
        if (OUT_BF16)
          ((unsigned short*)outv)[(size_t)row * N + col] = f2bf(v);
        else
          ((float*)outv)[(size_t)row * N + col] = v;
      }
    }
  }
}

template <bool RELU, int RESID_MODE, bool OUT_BF16>
__global__ __launch_bounds__(256, 2) void gemm_lds(
    const unsigned short* __restrict__ A, const unsigned short* __restrict__ Bt,
    const float* __restrict__ bias, const void* __restrict__ residv,
    void* __restrict__ outv, int M, int N, int K) {
  gemm_core<RELU, RESID_MODE, OUT_BF16>(A, Bt, bias, residv, outv, nullptr, M, N, K);
}

// z-batched QKV projection; z=2 (V) writes transposed VT[b][dh][s]
__global__ __launch_bounds__(256, 2) void gemm_qkv(
    const unsigned short* __restrict__ Abase, const unsigned short* __restrict__ Btbase,
    const float* __restrict__ b0, const float* __restrict__ b1, const float* __restrict__ b2,
    unsigned short* __restrict__ outbase, unsigned short* __restrict__ vtb) {
  const int z = blockIdx.z;
  const float* bp = (z == 0) ? b0 : (z == 1) ? b1 : b2;
  gemm_core<false, 0, true>(Abase + (size_t)z * 6291456, Btbase + (size_t)z * 589824,
                            bp, nullptr, outbase + (size_t)z * 6291456,
                            (z == 2) ? vtb : nullptr, 8192, 768, 768);
}

// ---------------- flash attention v6: symmetric K/VT staging, no-max softmax ----------------
// 4 waves x 32 q rows; swapped QK^T (lane owns a q-row), in-register softmax (T12),
// double-buffered LDS, one barrier/tile, T14 prefetch. V comes pre-transposed from the
// QKV GEMM (VT[b][dh][s]) so staging is b128 + XOR swizzle, identical to K — no scatter.
__global__ __launch_bounds__(256, 3) void flash_attn_v6(
    const unsigned short* __restrict__ qg, const unsigned short* __restrict__ kg,
    const unsigned short* __restrict__ vtg, const int* __restrict__ maskg,
    unsigned short* __restrict__ ctx) {
  __shared__ __align__(16) unsigned short Ks[2][64][64];
  __shared__ __align__(16) unsigned short Vt[2][64][64];
  __shared__ unsigned char TFlag[NT];

  const int t = threadIdx.x;
  const int L = t & 63, wv = t >> 6;
  const int q5 = L & 31, h5 = L >> 5;
  const int qb = blockIdx.x, h = blockIdx.y, b = blockIdx.z;
  const size_t bS = (size_t)b * S_;
  const int hb = h * DK_;
  const unsigned short* kbase = kg + bS * D_ + hb;
  const int* mp = maskg + bS;

  for (int tt = wv; tt < NT; tt += 4) {
    const int mv = mp[tt * KVB + L];
    const unsigned long long bal = __ballot(mv != 0);
    if (L == 0) TFlag[tt] = (bal == ~0ull) ? 1 : 0;
  }

  bf16x8 bq[4];
  {
    const unsigned short* qp = qg + (bS + qb * QBLK + wv * 32 + q5) * D_ + hb + h5 * 8;
#pragma unroll
    for (int ks = 0; ks < 4; ks++)
      bq[ks] = __builtin_bit_cast(bf16x8, *(const uint4*)(qp + ks * 16));
  }

  floatx16 o0, o1;
#pragma unroll
  for (int r = 0; r < 16; r++) { o0[r] = 0.f; o1[r] = 0.f; }
  float l_ = 0.f;

  const int srow = t >> 2, kc = (t & 3) * 2;   // staging: row srow, chunks kc,kc+1
  const unsigned short* vtbase = vtg + ((size_t)b * D_ + hb + srow) * 4096;  // row = d
  const int cshift = q5 & 7;

  uint4 kr0, kr1, vr0, vr1;
  {
    const unsigned short* kp = kbase + (size_t)srow * D_ + kc * 8;
    kr0 = *(const uint4*)kp; kr1 = *(const uint4*)(kp + 8);
    vr0 = *(const uint4*)(vtbase + kc * 8); vr1 = *(const uint4*)(vtbase + kc * 8 + 8);
    *(uint4*)&Ks[0][srow][((kc) ^ (srow & 7)) * 8] = kr0;
    *(uint4*)&Ks[0][srow][((kc + 1) ^ (srow & 7)) * 8] = kr1;
    *(uint4*)&Vt[0][srow][((kc) ^ (srow & 7)) * 8] = vr0;
    *(uint4*)&Vt[0][srow][((kc + 1) ^ (srow & 7)) * 8] = vr1;
  }
  __syncthreads();

  for (int kt = 0; kt < NT; kt++) {
    const int cur = kt & 1;
    const int kv0 = kt * KVB;
    if (kt + 1 < NT) {  // T14 prefetch (issue early, write late)
      const unsigned short* kp = kbase + (size_t)(kv0 + KVB + srow) * D_ + kc * 8;
      kr0 = *(const uint4*)kp; kr1 = *(const uint4*)(kp + 8);
      vr0 = *(const uint4*)(vtbase + kv0 + KVB + kc * 8);
      vr1 = *(const uint4*)(vtbase + kv0 + KVB + kc * 8 + 8);
    }

    // ---- S^T = K @ Q^T ----
    floatx16 s0, s1;
#pragma unroll
    for (int r = 0; r < 16; r++) { s0[r] = 0.f; s1[r] = 0.f; }
    __builtin_amdgcn_s_setprio(1);
#pragma unroll
    for (int ks = 0; ks < 4; ks++) {
      bf16x8 ak0 = __builtin_bit_cast(bf16x8, *(const uint4*)&Ks[cur][q5][(((ks << 1) | h5) ^ cshift) * 8]);
      bf16x8 ak1 = __builtin_bit_cast(bf16x8, *(const uint4*)&Ks[cur][32 + q5][(((ks << 1) | h5) ^ cshift) * 8]);
      s0 = __builtin_amdgcn_mfma_f32_32x32x16_bf16(ak0, bq[ks], s0, 0, 0, 0);
      s1 = __builtin_amdgcn_mfma_f32_32x32x16_bf16(ak1, bq[ks], s1, 0, 0, 0);
    }
    __builtin_amdgcn_s_setprio(0);

    // ---- scale (+mask bias) + clamp, exp2 directly (no max pass) ----
    const float csc = 0.180336880111120419f;  // 0.125 * log2(e)
    if (TFlag[kt]) {
#pragma unroll
      for (int r = 0; r < 16; r++) {
        s0[r] = fminf(fmaxf(s0[r] * csc, -88.f), 88.f);
        s1[r] = fminf(fmaxf(s1[r] * csc, -88.f), 88.f);
      }
    } else {
#pragma unroll
      for (int r = 0; r < 16; r++) {
        const int kvl = (r & 3) + 8 * (r >> 2) + 4 * h5;
        s0[r] = fminf(fmaxf(s0[r] * csc + (mp[kv0 + kvl] ? 0.f : -1e30f), -88.f), 88.f);
        s1[r] = fminf(fmaxf(s1[r] * csc + (mp[kv0 + 32 + kvl] ? 0.f : -1e30f), -88.f), 88.f);
      }
    }
#pragma unroll
    for (int r = 0; r < 16; r++) {
      s0[r] = exp2f(s0[r]);
      s1[r] = exp2f(s1[r]);
    }
    float a8[8];
#pragma unroll
    for (int i = 0; i < 8; i++) a8[i] = (s0[i] + s0[i + 8]) + (s1[i] + s1[i + 8]);
    float lsum = ((a8[0] + a8[1]) + (a8[2] + a8[3])) + ((a8[4] + a8[5]) + (a8[6] + a8[7]));
    lsum += __shfl_xor(lsum, 32, 64);
    l_ += lsum;

    // ---- P^T fragments: cvt_pk + permlane32_swap (T12) ----
    unsigned int w[16];
#pragma unroll
    for (int a = 0; a < 8; a++) {
      w[a] = cvtpk_bf16(s0[2 * a], s0[2 * a + 1]);
      w[8 + a] = cvtpk_bf16(s1[2 * a], s1[2 * a + 1]);
    }
#pragma unroll
    for (int ks = 0; ks < 4; ks++) {
      asm("v_permlane32_swap_b32 %0, %1" : "+v"(w[4 * ks]), "+v"(w[4 * ks + 2]));
      asm("v_permlane32_swap_b32 %0, %1" : "+v"(w[4 * ks + 1]), "+v"(w[4 * ks + 3]));
    }

    // ---- O^T += V^T @ P^T ----
    __builtin_amdgcn_s_setprio(1);
#pragma unroll
    for (int ks = 0; ks < 4; ks++) {
      const bf16x8 pa = __builtin_bit_cast(bf16x8,
          make_uint4(w[4 * ks], w[4 * ks + 1], w[4 * ks + 2], w[4 * ks + 3]));
      bf16x8 av0 = __builtin_bit_cast(bf16x8, *(const uint4*)&Vt[cur][q5][(((ks << 1) | h5) ^ cshift) * 8]);
      bf16x8 av1 = __builtin_bit_cast(bf16x8, *(const uint4*)&Vt[cur][32 + q5][(((ks << 1) | h5) ^ cshift) * 8]);
      o0 = __builtin_amdgcn_mfma_f32_32x32x16_bf16(av0, pa, o0, 0, 0, 0);
      o1 = __builtin_amdgcn_mfma_f32_32x32x16_bf16(av1, pa, o1, 0, 0, 0);
    }
    __builtin_amdgcn_s_setprio(0);

    // ---- stage tile kt+1 into buf[cur^1] (write-late half of T14) ----
    if (kt + 1 < NT) {
      *(uint4*)&Ks[cur ^ 1][srow][((kc) ^ (srow & 7)) * 8] = kr0;
      *(uint4*)&Ks[cur ^ 1][srow][((kc + 1) ^ (srow & 7)) * 8] = kr1;
      *(uint4*)&Vt[cur ^ 1][srow][((kc) ^ (srow & 7)) * 8] = vr0;
      *(uint4*)&Vt[cur ^ 1][srow][((kc + 1) ^ (srow & 7)) * 8] = vr1;
    }
    __syncthreads();
  }

  {
    const float inv = 1.f / l_;
    unsigned int ep[16];
#pragma unroll
    for (int a = 0; a < 8; a++) {
      ep[a] = cvtpk_bf16(o0[2 * a] * inv, o0[2 * a + 1] * inv);
      ep[8 + a] = cvtpk_bf16(o1[2 * a] * inv, o1[2 * a + 1] * inv);
    }
    unsigned short* crow = ctx + (bS + qb * QBLK + wv * 32 + q5) * D_ + hb;
#pragma unroll
    for (int dt = 0; dt < 2; dt++)
#pragma unroll
      for (int g4 = 0; g4 < 4; g4++)
        *(uint2*)(crow + dt * 32 + g4 * 8 + h5 * 4) =
            make_uint2(ep[dt * 8 + g4 * 2], ep[dt * 8 + g4 * 2 + 1]);
  }
}

// ---------------- LayerNorm over rows of 768 ----------------
template <bool OUT_BF16>
__global__ __launch_bounds__(256) void ln_kernel(const float* __restrict__ x,
                                                 const float* __restrict__ g,
                                                 const float* __restrict__ be,
                                                 void* __restrict__ outv) {
  __shared__ float red[4];
  const int t = threadIdx.x, lane = t & 63, wave = t >> 6;
  const size_t row = blockIdx.x;
  const float* xr = x + row * D_;
  float v0 = xr[t], v1 = xr[t + 256], v2 = xr[t + 512];
  float s = v0 + v1 + v2;
#pragma unroll
  for (int off = 32; off; off >>= 1) s += __shfl_xor(s, off, 64);
  if (lane == 0) red[wave] = s;
  __syncthreads();
  const float mu = (red[0] + red[1] + red[2] + red[3]) * (1.f / 768.f);
  __syncthreads();
  const float d0 = v0 - mu, d1 = v1 - mu, d2 = v2 - mu;
  float vs = d0 * d0 + d1 * d1 + d2 * d2;
#pragma unroll
  for (int off = 32; off; off >>= 1) vs += __shfl_xor(vs, off, 64);
  if (lane == 0) red[wave] = vs;
  __syncthreads();
  const float rs = rsqrtf((red[0] + red[1] + red[2] + red[3]) * (1.f / 768.f) + 1e-6f);
  const float r0v = d0 * rs * g[t] + be[t];
  const float r1v = d1 * rs * g[t + 256] + be[t + 256];
  const float r2v = d2 * rs * g[t + 512] + be[t + 512];
  if (OUT_BF16) {
    unsigned short* o = (unsigned short*)outv + row * D_;
    o[t] = f2bf(r0v); o[t + 256] = f2bf(r1v); o[t + 512] = f2bf(r2v);
  } else {
    float* o = (float*)outv + row * D_;
    o[t] = r0v; o[t + 256] = r1v; o[t + 512] = r2v;
  }
}

// ---------------- host launcher ----------------
extern "C" void kernel_launch(void* const* d_in, const int* in_sizes, int n_in,
                              void* d_out, int out_size, void* d_ws, size_t ws_size,
                              hipStream_t stream) {
  const float* xq = (const float*)d_in[0];
  const float* xk = (const float*)d_in[1];
  const float* xv = (const float*)d_in[2];
  const int* mask = (const int*)d_in[3];
  const float* wq = (const float*)d_in[4];
  const float* bq = (const float*)d_in[5];
  const float* wk = (const float*)d_in[6];
  const float* bk = (const float*)d_in[7];
  const float* wv = (const float*)d_in[8];
  const float* bv = (const float*)d_in[9];
  const float* wo = (const float*)d_in[10];
  const float* bo = (const float*)d_in[11];
  const float* w1 = (const float*)d_in[12];
  const float* b1 = (const float*)d_in[13];
  const float* w2 = (const float*)d_in[14];
  const float* b2 = (const float*)d_in[15];
  const float* g1 = (const float*)d_in[16];
  const float* be1 = (const float*)d_in[17];
  const float* g2 = (const float*)d_in[18];
  const float* be2 = (const float*)d_in[19];
  float* out = (float*)d_out;
  char* ws = (char*)d_ws;

  // workspace layout (bytes); high water 114819072 (known-safe)
  unsigned short* WQT = (unsigned short*)(ws + 0);          // WQT..WOT contiguous
  unsigned short* W1T = (unsigned short*)(ws + 4718592);
  unsigned short* W2T = (unsigned short*)(ws + 9437184);
  unsigned short* XQB = (unsigned short*)(ws + 14155776);   // XQB/XKB/XVB contiguous
  unsigned short* QB = (unsigned short*)(ws + 51904512);    // QB/KB contiguous (z=0,1)
  unsigned short* VTB = (unsigned short*)(ws + 77070336);   // V transposed [b][dh][s]
  unsigned short* CTXB = (unsigned short*)(ws + 14155776);  // alias XQB (dead post-QKV)
  float* X1PRE = (float*)(ws + 51904512);                   // alias QB+KB (dead post-flash)
  unsigned short* X1B = (unsigned short*)(ws + 77070336);   // alias VTB (dead post-flash)
  unsigned short* HB = (unsigned short*)(ws + 14155776);    // alias CTXB region (dead)
  float* X2PRE = (float*)(ws + 89653248);
  unsigned short* WOT = WQT + 3 * 589824;

  wtrans4<<<dim3(24, 24, 4), 256, 0, stream>>>(wq, wk, wv, wo, WQT);
  wtrans<<<dim3(96, 24), 256, 0, stream>>>(w1, W1T, 768, 3072);
  wtrans<<<dim3(24, 96), 256, 0, stream>>>(w2, W2T, 3072, 768);

  cvt_bf16_3<<<dim3(3072, 1, 3), 256, 0, stream>>>(xq, xk, xv, XQB, 786432);

  gemm_qkv<<<dim3(6, 64, 3), 256, 0, stream>>>(XQB, WQT, bq, bk, bv, QB, VTB);

  flash_attn_v6<<<dim3(S_ / QBLK, H_, B_), 256, 0, stream>>>(QB, QB + 6291456, VTB, mask, CTXB);

  gemm_lds<false, 1, false><<<dim3(6, 64), 256, 0, stream>>>(CTXB, WOT, bo, xq, X1PRE, 8192, 768, 768);

  ln_kernel<true><<<8192, 256, 0, stream>>>(X1PRE, g1, be1, X1B);

  gemm_lds<true, 0, true><<<dim3(24, 64), 256, 0, stream>>>(X1B, W1T, b1, nullptr, HB, 8192, 3072, 768);

  gemm_lds<false, 2, false><<<dim3(6, 64), 256, 0, stream>>>(HB, W2T, b2, X1B, X2PRE, 8192, 768, 3072);

  ln_kernel<false><<<8192, 256, 0, stream>>>(X2PRE, g2, be2, out);
}

// Round 10
// 408.227 us; speedup vs baseline: 1.1568x; 1.0133x over previous
//
#include <hip/hip_runtime.h>
#include <stdint.h>

#define B_ 2
#define S_ 4096
#define D_ 768
#define H_ 12
#define F_ 3072
#define DK_ 64
#define QBLK 128
#define KVB 64
#define NT (S_ / KVB)

typedef __bf16 bf16x8 __attribute__((ext_vector_type(8)));
typedef float floatx4 __attribute__((ext_vector_type(4)));
typedef float floatx16 __attribute__((ext_vector_type(16)));

__device__ __forceinline__ float bf2f(unsigned short u) {
  unsigned int x = ((unsigned int)u) << 16;
  return __builtin_bit_cast(float, x);
}
__device__ __forceinline__ unsigned short f2bf(float f) {
  unsigned int x = __builtin_bit_cast(unsigned int, f);
  x += 0x7FFFu + ((x >> 16) & 1u);
  return (unsigned short)(x >> 16);
}
__device__ __forceinline__ unsigned int cvtpk_bf16(float lo, float hi) {
  unsigned int r;
  asm("v_cvt_pk_bf16_f32 %0, %1, %2" : "=v"(r) : "v"(lo), "v"(hi));
  return r;
}

// ---------------- weight transpose + cvt: w[K][N] f32 -> wt[N][K] bf16 ----------------
__device__ __forceinline__ void wtrans_core(const float* __restrict__ w,
                                            unsigned short* __restrict__ wt,
                                            int K, int N) {
  __shared__ float tile[32][33];
  const int n0 = blockIdx.x * 32, k0 = blockIdx.y * 32;
  const int tx = threadIdx.x & 31, ty8 = threadIdx.x >> 5;
#pragma unroll
  for (int r = 0; r < 4; r++)
    tile[ty8 + r * 8][tx] = w[(size_t)(k0 + ty8 + r * 8) * N + n0 + tx];
  __syncthreads();
#pragma unroll
  for (int r = 0; r < 4; r++)
    wt[(size_t)(n0 + ty8 + r * 8) * K + k0 + tx] = f2bf(tile[tx][ty8 + r * 8]);
}

__global__ __launch_bounds__(256) void wtrans(const float* __restrict__ w,
                                              unsigned short* __restrict__ wt,
                                              int K, int N) {
  wtrans_core(w, wt, K, N);
}

__global__ __launch_bounds__(256) void wtrans4(const float* __restrict__ w0,
                                               const float* __restrict__ w1,
                                               const float* __restrict__ w2,
                                               const float* __restrict__ w3,
                                               unsigned short* __restrict__ wtbase) {
  const int z = blockIdx.z;
  const float* w = (z == 0) ? w0 : (z == 1) ? w1 : (z == 2) ? w2 : w3;
  wtrans_core(w, wtbase + (size_t)z * 589824, 768, 768);
}

// ---------------- f32 -> bf16 bulk convert, z-batched over 3 inputs ----------------
__global__ __launch_bounds__(256) void cvt_bf16_3(const float* __restrict__ x0,
                                                  const float* __restrict__ x1,
                                                  const float* __restrict__ x2,
                                                  unsigned short* __restrict__ ybase, int n8) {
  const int z = blockIdx.z;
  const float* x = (z == 0) ? x0 : (z == 1) ? x1 : x2;
  unsigned short* y = ybase + (size_t)z * 6291456;
  const int i = blockIdx.x * 256 + threadIdx.x;
  if (i >= n8) return;
  const float4 a = ((const float4*)x)[2 * i];
  const float4 b = ((const float4*)x)[2 * i + 1];
  uint4 o;
  o.x = (unsigned int)f2bf(a.x) | ((unsigned int)f2bf(a.y) << 16);
  o.y = (unsigned int)f2bf(a.z) | ((unsigned int)f2bf(a.w) << 16);
  o.z = (unsigned int)f2bf(b.x) | ((unsigned int)f2bf(b.y) << 16);
  o.w = (unsigned int)f2bf(b.z) | ((unsigned int)f2bf(b.w) << 16);
  ((uint4*)y)[i] = o;
}

// ---------------- GEMM core (m97 structure, BK=64) ----------------
// RESID_MODE: 0 none, 1 f32, 2 bf16. oscale multiplies (acc+bias) before output
// (used to pre-scale Q by 0.125*log2e). If vtout != nullptr: write transposed
// VT[b][col][s] (b = row>>12, s = row&4095) instead of row-major out.
template <bool RELU, int RESID_MODE, bool OUT_BF16>
__device__ __forceinline__ void gemm_core(
    const unsigned short* __restrict__ A, const unsigned short* __restrict__ Bt,
    const float* __restrict__ bias, const void* __restrict__ residv,
    void* __restrict__ outv, unsigned short* __restrict__ vtout,
    float oscale, int M, int N, int K) {
  __shared__ __align__(16) unsigned short As[128 * 64];
  __shared__ __align__(16) unsigned short Bs[128 * 64];
  int bx = blockIdx.x, by = blockIdx.y;
  {
    const int gx = gridDim.x;
    const int nwg = gx * gridDim.y;       // all grids divisible by 8
    const int flat = by * gx + bx;
    const int wg = (flat & 7) * (nwg >> 3) + (flat >> 3);
    bx = wg % gx; by = wg / gx;
  }
  const int t = threadIdx.x;
  const int lane = t & 63, wave = t >> 6;
  const int m0 = by * 128, n0 = bx * 128;
  const int wm = (wave >> 1) * 64, wn = (wave & 1) * 64;
  const int rl = lane & 15, kl = (lane >> 4) * 8;
  const int lrow = lane >> 3, lcol = (lane & 7) * 8;

  floatx4 zf = {0.f, 0.f, 0.f, 0.f};
  floatx4 acc[4][4];
#pragma unroll
  for (int i = 0; i < 4; i++)
#pragma unroll
    for (int j = 0; j < 4; j++) acc[i][j] = zf;

  const unsigned short* Ab = A + (size_t)(m0 + wave * 32 + lrow) * K + lcol;
  const unsigned short* Bb = Bt + (size_t)(n0 + wave * 32 + lrow) * K + lcol;
  unsigned short* AsW = As + wave * 2048;
  unsigned short* BsW = Bs + wave * 2048;

  for (int k0 = 0; k0 < K; k0 += 64) {
    __syncthreads();
#pragma unroll
    for (int ld = 0; ld < 4; ld++) {
      __builtin_amdgcn_global_load_lds(Ab + k0 + (size_t)(ld * 8) * K, AsW + ld * 512, 16, 0, 0);
      __builtin_amdgcn_global_load_lds(Bb + k0 + (size_t)(ld * 8) * K, BsW + ld * 512, 16, 0, 0);
    }
    __syncthreads();
#pragma unroll
    for (int ks = 0; ks < 2; ks++) {
      bf16x8 af[4], bff[4];
#pragma unroll
      for (int i = 0; i < 4; i++)
        af[i] = __builtin_bit_cast(bf16x8, *(const uint4*)&As[(wm + i * 16 + rl) * 64 + ks * 32 + kl]);
#pragma unroll
      for (int j = 0; j < 4; j++)
        bff[j] = __builtin_bit_cast(bf16x8, *(const uint4*)&Bs[(wn + j * 16 + rl) * 64 + ks * 32 + kl]);
#pragma unroll
      for (int i = 0; i < 4; i++)
#pragma unroll
        for (int j = 0; j < 4; j++)
          acc[i][j] = __builtin_amdgcn_mfma_f32_16x16x32_bf16(af[i], bff[j], acc[i][j], 0, 0, 0);
    }
  }

  const int r0 = (lane >> 4) * 4;
  if (vtout) {
#pragma unroll
    for (int i = 0; i < 4; i++) {
#pragma unroll
      for (int j = 0; j < 4; j++) {
        const int col = n0 + wn + j * 16 + rl;
        const float bv = bias[col];
        const int rowb = m0 + wm + i * 16 + r0;
        const int bb = rowb >> 12, s = rowb & 4095;
        unsigned short e[4];
#pragma unroll
        for (int r = 0; r < 4; r++) e[r] = f2bf(acc[i][j][r] + bv);
        *(uint2*)&vtout[((size_t)bb * D_ + col) * 4096 + s] =
            make_uint2((unsigned int)e[0] | ((unsigned int)e[1] << 16),
                       (unsigned int)e[2] | ((unsigned int)e[3] << 16));
      }
    }
    return;
  }
#pragma unroll
  for (int i = 0; i < 4; i++) {
#pragma unroll
    for (int j = 0; j < 4; j++) {
      const int col = n0 + wn + j * 16 + rl;
      const float bv = bias[col];
#pragma unroll
      for (int r = 0; r < 4; r++) {
        const int row = m0 + wm + i * 16 + r0 + r;
        float v = (acc[i][j][r] + bv) * oscale;
        if (RESID_MODE == 1) v += ((const float*)residv)[(size_t)row * N + col];
        if (RESID_MODE == 2) v += bf2f(((const unsigned short*)residv)[(size_t)row * N + col]);
        if (RELU) v = v > 0.f ? v : 0.f;
        if (OUT_BF16)
          ((unsigned short*)outv)[(size_t)row * N + col] = f2bf(v);
        else
          ((float*)outv)[(size_t)row * N + col] = v;
      }
    }
  }
}

template <bool RELU, int RESID_MODE, bool OUT_BF16>
__global__ __launch_bounds__(256, 3) void gemm_lds(
    const unsigned short* __restrict__ A, const unsigned short* __restrict__ Bt,
    const float* __restrict__ bias, const void* __restrict__ residv,
    void* __restrict__ outv, int M, int N, int K) {
  gemm_core<RELU, RESID_MODE, OUT_BF16>(A, Bt, bias, residv, outv, nullptr, 1.0f, M, N, K);
}

// z-batched QKV projection; z=0 (Q) pre-scaled by 0.125*log2e; z=2 (V) writes VT[b][dh][s]
__global__ __launch_bounds__(256, 3) void gemm_qkv(
    const unsigned short* __restrict__ Abase, const unsigned short* __restrict__ Btbase,
    const float* __restrict__ b0, const float* __restrict__ b1, const float* __restrict__ b2,
    unsigned short* __restrict__ outbase, unsigned short* __restrict__ vtb) {
  const int z = blockIdx.z;
  const float* bp = (z == 0) ? b0 : (z == 1) ? b1 : b2;
  const float sc = (z == 0) ? 0.180336880111120419f : 1.0f;  // 0.125 * log2(e)
  gemm_core<false, 0, true>(Abase + (size_t)z * 6291456, Btbase + (size_t)z * 589824,
                            bp, nullptr, outbase + (size_t)z * 6291456,
                            (z == 2) ? vtb : nullptr, sc, 8192, 768, 768);
}

// ---------------- flash attention v7: prescaled Q, upper-clamp-only no-max softmax ----------------
// 4 waves x 32 q rows; swapped QK^T (lane owns a q-row), in-register softmax (T12),
// double-buffered LDS, one barrier/tile, T14 prefetch, symmetric K/VT b128 staging.
// Q arrives pre-scaled by 0.125*log2(e), so scores are already in log2 units:
// p = exp2(min(s + maskbias, 88)); exp2(very negative) underflows to 0 cleanly.
__global__ __launch_bounds__(256, 3) void flash_attn_v7(
    const unsigned short* __restrict__ qg, const unsigned short* __restrict__ kg,
    const unsigned short* __restrict__ vtg, const int* __restrict__ maskg,
    unsigned short* __restrict__ ctx) {
  __shared__ __align__(16) unsigned short Ks[2][64][64];
  __shared__ __align__(16) unsigned short Vt[2][64][64];
  __shared__ unsigned char TFlag[NT];

  const int t = threadIdx.x;
  const int L = t & 63, wv = t >> 6;
  const int q5 = L & 31, h5 = L >> 5;
  const int qb = blockIdx.x, h = blockIdx.y, b = blockIdx.z;
  const size_t bS = (size_t)b * S_;
  const int hb = h * DK_;
  const unsigned short* kbase = kg + bS * D_ + hb;
  const int* mp = maskg + bS;

  for (int tt = wv; tt < NT; tt += 4) {
    const int mv = mp[tt * KVB + L];
    const unsigned long long bal = __ballot(mv != 0);
    if (L == 0) TFlag[tt] = (bal == ~0ull) ? 1 : 0;
  }

  bf16x8 bq[4];
  {
    const unsigned short* qp = qg + (bS + qb * QBLK + wv * 32 + q5) * D_ + hb + h5 * 8;
#pragma unroll
    for (int ks = 0; ks < 4; ks++)
      bq[ks] = __builtin_bit_cast(bf16x8, *(const uint4*)(qp + ks * 16));
  }

  floatx16 o0, o1;
#pragma unroll
  for (int r = 0; r < 16; r++) { o0[r] = 0.f; o1[r] = 0.f; }
  float l_ = 0.f;

  const int srow = t >> 2, kc = (t & 3) * 2;
  const unsigned short* vtbase = vtg + ((size_t)b * D_ + hb + srow) * 4096;
  const int cshift = q5 & 7;

  uint4 kr0, kr1, vr0, vr1;
  {
    const unsigned short* kp = kbase + (size_t)srow * D_ + kc * 8;
    kr0 = *(const uint4*)kp; kr1 = *(const uint4*)(kp + 8);
    vr0 = *(const uint4*)(vtbase + kc * 8); vr1 = *(const uint4*)(vtbase + kc * 8 + 8);
    *(uint4*)&Ks[0][srow][((kc) ^ (srow & 7)) * 8] = kr0;
    *(uint4*)&Ks[0][srow][((kc + 1) ^ (srow & 7)) * 8] = kr1;
    *(uint4*)&Vt[0][srow][((kc) ^ (srow & 7)) * 8] = vr0;
    *(uint4*)&Vt[0][srow][((kc + 1) ^ (srow & 7)) * 8] = vr1;
  }
  __syncthreads();

  for (int kt = 0; kt < NT; kt++) {
    const int cur = kt & 1;
    const int kv0 = kt * KVB;
    if (kt + 1 < NT) {  // T14 prefetch (issue early, write late)
      const unsigned short* kp = kbase + (size_t)(kv0 + KVB + srow) * D_ + kc * 8;
      kr0 = *(const uint4*)kp; kr1 = *(const uint4*)(kp + 8);
      vr0 = *(const uint4*)(vtbase + kv0 + KVB + kc * 8);
      vr1 = *(const uint4*)(vtbase + kv0 + KVB + kc * 8 + 8);
    }

    // ---- S^T = K @ Q^T (Q pre-scaled: s is already log2-domain) ----
    floatx16 s0, s1;
#pragma unroll
    for (int r = 0; r < 16; r++) { s0[r] = 0.f; s1[r] = 0.f; }
    __builtin_amdgcn_s_setprio(1);
#pragma unroll
    for (int ks = 0; ks < 4; ks++) {
      bf16x8 ak0 = __builtin_bit_cast(bf16x8, *(const uint4*)&Ks[cur][q5][(((ks << 1) | h5) ^ cshift) * 8]);
      bf16x8 ak1 = __builtin_bit_cast(bf16x8, *(const uint4*)&Ks[cur][32 + q5][(((ks << 1) | h5) ^ cshift) * 8]);
      s0 = __builtin_amdgcn_mfma_f32_32x32x16_bf16(ak0, bq[ks], s0, 0, 0, 0);
      s1 = __builtin_amdgcn_mfma_f32_32x32x16_bf16(ak1, bq[ks], s1, 0, 0, 0);
    }
    __builtin_amdgcn_s_setprio(0);

    // ---- upper clamp (+mask bias on slow path), then exp2 ----
    if (TFlag[kt]) {
#pragma unroll
      for (int r = 0; r < 16; r++) {
        s0[r] = fminf(s0[r], 88.f);
        s1[r] = fminf(s1[r], 88.f);
      }
    } else {
#pragma unroll
      for (int r = 0; r < 16; r++) {
        const int kvl = (r & 3) + 8 * (r >> 2) + 4 * h5;
        s0[r] = fminf(s0[r] + (mp[kv0 + kvl] ? 0.f : -1e30f), 88.f);
        s1[r] = fminf(s1[r] + (mp[kv0 + 32 + kvl] ? 0.f : -1e30f), 88.f);
      }
    }
#pragma unroll
    for (int r = 0; r < 16; r++) {
      s0[r] = exp2f(s0[r]);
      s1[r] = exp2f(s1[r]);
    }
    float a8[8];
#pragma unroll
    for (int i = 0; i < 8; i++) a8[i] = (s0[i] + s0[i + 8]) + (s1[i] + s1[i + 8]);
    float lsum = ((a8[0] + a8[1]) + (a8[2] + a8[3])) + ((a8[4] + a8[5]) + (a8[6] + a8[7]));
    lsum += __shfl_xor(lsum, 32, 64);
    l_ += lsum;

    // ---- P^T fragments: cvt_pk + permlane32_swap (T12) ----
    unsigned int w[16];
#pragma unroll
    for (int a = 0; a < 8; a++) {
      w[a] = cvtpk_bf16(s0[2 * a], s0[2 * a + 1]);
      w[8 + a] = cvtpk_bf16(s1[2 * a], s1[2 * a + 1]);
    }
#pragma unroll
    for (int ks = 0; ks < 4; ks++) {
      asm("v_permlane32_swap_b32 %0, %1" : "+v"(w[4 * ks]), "+v"(w[4 * ks + 2]));
      asm("v_permlane32_swap_b32 %0, %1" : "+v"(w[4 * ks + 1]), "+v"(w[4 * ks + 3]));
    }

    // ---- O^T += V^T @ P^T ----
    __builtin_amdgcn_s_setprio(1);
#pragma unroll
    for (int ks = 0; ks < 4; ks++) {
      const bf16x8 pa = __builtin_bit_cast(bf16x8,
          make_uint4(w[4 * ks], w[4 * ks + 1], w[4 * ks + 2], w[4 * ks + 3]));
      bf16x8 av0 = __builtin_bit_cast(bf16x8, *(const uint4*)&Vt[cur][q5][(((ks << 1) | h5) ^ cshift) * 8]);
      bf16x8 av1 = __builtin_bit_cast(bf16x8, *(const uint4*)&Vt[cur][32 + q5][(((ks << 1) | h5) ^ cshift) * 8]);
      o0 = __builtin_amdgcn_mfma_f32_32x32x16_bf16(av0, pa, o0, 0, 0, 0);
      o1 = __builtin_amdgcn_mfma_f32_32x32x16_bf16(av1, pa, o1, 0, 0, 0);
    }
    __builtin_amdgcn_s_setprio(0);

    // ---- stage tile kt+1 into buf[cur^1] (write-late half of T14) ----
    if (kt + 1 < NT) {
      *(uint4*)&Ks[cur ^ 1][srow][((kc) ^ (srow & 7)) * 8] = kr0;
      *(uint4*)&Ks[cur ^ 1][srow][((kc + 1) ^ (srow & 7)) * 8] = kr1;
      *(uint4*)&Vt[cur ^ 1][srow][((kc) ^ (srow & 7)) * 8] = vr0;
      *(uint4*)&Vt[cur ^ 1][srow][((kc + 1) ^ (srow & 7)) * 8] = vr1;
    }
    __syncthreads();
  }

  {
    const float inv = 1.f / l_;
    unsigned int ep[16];
#pragma unroll
    for (int a = 0; a < 8; a++) {
      ep[a] = cvtpk_bf16(o0[2 * a] * inv, o0[2 * a + 1] * inv);
      ep[8 + a] = cvtpk_bf16(o1[2 * a] * inv, o1[2 * a + 1] * inv);
    }
    unsigned short* crow = ctx + (bS + qb * QBLK + wv * 32 + q5) * D_ + hb;
#pragma unroll
    for (int dt = 0; dt < 2; dt++)
#pragma unroll
      for (int g4 = 0; g4 < 4; g4++)
        *(uint2*)(crow + dt * 32 + g4 * 8 + h5 * 4) =
            make_uint2(ep[dt * 8 + g4 * 2], ep[dt * 8 + g4 * 2 + 1]);
  }
}

// ---------------- LayerNorm over rows of 768 ----------------
template <bool OUT_BF16>
__global__ __launch_bounds__(256) void ln_kernel(const float* __restrict__ x,
                                                 const float* __restrict__ g,
                                                 const float* __restrict__ be,
                                                 void* __restrict__ outv) {
  __shared__ float red[4];
  const int t = threadIdx.x, lane = t & 63, wave = t >> 6;
  const size_t row = blockIdx.x;
  const float* xr = x + row * D_;
  float v0 = xr[t], v1 = xr[t + 256], v2 = xr[t + 512];
  float s = v0 + v1 + v2;
#pragma unroll
  for (int off = 32; off; off >>= 1) s += __shfl_xor(s, off, 64);
  if (lane == 0) red[wave] = s;
  __syncthreads();
  const float mu = (red[0] + red[1] + red[2] + red[3]) * (1.f / 768.f);
  __syncthreads();
  const float d0 = v0 - mu, d1 = v1 - mu, d2 = v2 - mu;
  float vs = d0 * d0 + d1 * d1 + d2 * d2;
#pragma unroll
  for (int off = 32; off; off >>= 1) vs += __shfl_xor(vs, off, 64);
  if (lane == 0) red[wave] = vs;
  __syncthreads();
  const float rs = rsqrtf((red[0] + red[1] + red[2] + red[3]) * (1.f / 768.f) + 1e-6f);
  const float r0v = d0 * rs * g[t] + be[t];
  const float r1v = d1 * rs * g[t + 256] + be[t + 256];
  const float r2v = d2 * rs * g[t + 512] + be[t + 512];
  if (OUT_BF16) {
    unsigned short* o = (unsigned short*)outv + row * D_;
    o[t] = f2bf(r0v); o[t + 256] = f2bf(r1v); o[t + 512] = f2bf(r2v);
  } else {
    float* o = (float*)outv + row * D_;
    o[t] = r0v; o[t + 256] = r1v; o[t + 512] = r2v;
  }
}

// ---------------- host launcher ----------------
extern "C" void kernel_launch(void* const* d_in, const int* in_sizes, int n_in,
                              void* d_out, int out_size, void* d_ws, size_t ws_size,
                              hipStream_t stream) {
  const float* xq = (const float*)d_in[0];
  const float* xk = (const float*)d_in[1];
  const float* xv = (const float*)d_in[2];
  const int* mask = (const int*)d_in[3];
  const float* wq = (const float*)d_in[4];
  const float* bq = (const float*)d_in[5];
  const float* wk = (const float*)d_in[6];
  const float* bk = (const float*)d_in[7];
  const float* wv = (const float*)d_in[8];
  const float* bv = (const float*)d_in[9];
  const float* wo = (const float*)d_in[10];
  const float* bo = (const float*)d_in[11];
  const float* w1 = (const float*)d_in[12];
  const float* b1 = (const float*)d_in[13];
  const float* w2 = (const float*)d_in[14];
  const float* b2 = (const float*)d_in[15];
  const float* g1 = (const float*)d_in[16];
  const float* be1 = (const float*)d_in[17];
  const float* g2 = (const float*)d_in[18];
  const float* be2 = (const float*)d_in[19];
  float* out = (float*)d_out;
  char* ws = (char*)d_ws;

  // workspace layout (bytes); high water 114819072 (known-safe)
  unsigned short* WQT = (unsigned short*)(ws + 0);          // WQT..WOT contiguous
  unsigned short* W1T = (unsigned short*)(ws + 4718592);
  unsigned short* W2T = (unsigned short*)(ws + 9437184);
  unsigned short* XQB = (unsigned short*)(ws + 14155776);   // XQB/XKB/XVB contiguous
  unsigned short* QB = (unsigned short*)(ws + 51904512);    // QB/KB contiguous (z=0,1)
  unsigned short* VTB = (unsigned short*)(ws + 77070336);   // V transposed [b][dh][s]
  unsigned short* CTXB = (unsigned short*)(ws + 14155776);  // alias XQB (dead post-QKV)
  float* X1PRE = (float*)(ws + 51904512);                   // alias QB+KB (dead post-flash)
  unsigned short* X1B = (unsigned short*)(ws + 77070336);   // alias VTB (dead post-flash)
  unsigned short* HB = (unsigned short*)(ws + 14155776);    // alias CTXB region (dead)
  float* X2PRE = (float*)(ws + 89653248);
  unsigned short* WOT = WQT + 3 * 589824;

  wtrans4<<<dim3(24, 24, 4), 256, 0, stream>>>(wq, wk, wv, wo, WQT);
  wtrans<<<dim3(96, 24), 256, 0, stream>>>(w1, W1T, 768, 3072);
  wtrans<<<dim3(24, 96), 256, 0, stream>>>(w2, W2T, 3072, 768);

  cvt_bf16_3<<<dim3(3072, 1, 3), 256, 0, stream>>>(xq, xk, xv, XQB, 786432);

  gemm_qkv<<<dim3(6, 64, 3), 256, 0, stream>>>(XQB, WQT, bq, bk, bv, QB, VTB);

  flash_attn_v7<<<dim3(S_ / QBLK, H_, B_), 256, 0, stream>>>(QB, QB + 6291456, VTB, mask, CTXB);

  gemm_lds<false, 1, false><<<dim3(6, 64), 256, 0, stream>>>(CTXB, WOT, bo, xq, X1PRE, 8192, 768, 768);

  ln_kernel<true><<<8192, 256, 0, stream>>>(X1PRE, g1, be1, X1B);

  gemm_lds<true, 0, true><<<dim3(24, 64), 256, 0, stream>>>(X1B, W1T, b1, nullptr, HB, 8192, 3072, 768);

  gemm_lds<false, 2, false><<<dim3(6, 64), 256, 0, stream>>>(HB, W2T, b2, X1B, X2PRE, 8192, 768, 3072);

  ln_kernel<false><<<8192, 256, 0, stream>>>(X2PRE, g2, be2, out);
}